// Round 7
// baseline (2391.677 us; speedup 1.0000x reference)
//
#include <hip/hip_runtime.h>
#include <math.h>

// ---------------------------------------------------------------------------
// VQSign r15: halve weight L2 redundancy in conv2k/conv3k. Six rounds of
// evidence: conv3k is pinned at 110-117us regardless of FETCH (10-55MB),
// conflicts (0-5.3M), VALU (9-15%) -> the binding term is the 4x-redundant
// per-step weight stream (4 waves x 8KB same slice = 32KB issued / 8KB unique
// per block-step ~ 5MB/CU through L1/L2). r15 re-maps waves: each wave owns
// 2 rows x 32 co (lrow=(w&1)*2, h2=w>>1): weight loads/step 8->4 (traffic
// halved), B ds_reads 4->8 (LDS cheap). MFMA chain per output unchanged ->
// conv outputs bit-identical (stats grouping shifts within the tolerance the
// nondeterministic cross-block atomics already require). conv3k uses r13's
// proven XOR layout; conv2k keeps r14's padded layout. projk: d-tiled
// (8 d/block) -> enc re-read 940MB -> 117MB, float4 loads.
// ---------------------------------------------------------------------------

typedef __attribute__((ext_vector_type(8))) short short8;
typedef __attribute__((ext_vector_type(4))) float f32x4;

__device__ inline unsigned short f2bf(float x) {
    unsigned int u = __float_as_uint(x);
    u += 0x7FFFu + ((u >> 16) & 1u);          // RNE
    return (unsigned short)(u >> 16);
}
__device__ inline float bf2f(unsigned short h) {
    return __uint_as_float(((unsigned int)h) << 16);
}
__device__ inline f32x4 vmax4(f32x4 a, f32x4 b) {
    return (f32x4){fmaxf(a.x, b.x), fmaxf(a.y, b.y), fmaxf(a.z, b.z), fmaxf(a.w, b.w)};
}
__device__ inline f32x4 vmin4(f32x4 a, f32x4 b) {
    return (f32x4){fminf(a.x, b.x), fminf(a.y, b.y), fminf(a.z, b.z), fminf(a.w, b.w)};
}

#define MF(d, a, b) d = __builtin_amdgcn_mfma_f32_16x16x32_bf16(a, b, d, 0, 0, 0)

// ---------------- conv1: fp32, LDS tile, pooled max/min chan-last out -------
#define C1LOADR(J) \
    f32x4 u = *(const f32x4*)(ip + (J) * 36); \
    f32x4 w4 = *(const f32x4*)(ip + (J) * 36 + 4); \
    f32x4 sA = u; \
    f32x4 sB = __builtin_shufflevector(u, w4, 1, 2, 3, 4); \
    f32x4 sC = __builtin_shufflevector(u, w4, 2, 3, 4, 5);
#define C1UPD0(I) a0_##I += wa0 * sA + wa1 * sB + wa2 * sC; a1_##I += wb0 * sA + wb1 * sB + wb2 * sC;
#define C1UPD1(I) a0_##I += wa3 * sA + wa4 * sB + wa5 * sC; a1_##I += wb3 * sA + wb4 * sB + wb5 * sC;
#define C1UPD2(I) a0_##I += wa6 * sA + wa7 * sB + wa8 * sC; a1_##I += wb6 * sA + wb7 * sB + wb8 * sC;

__launch_bounds__(256, 3)
__global__ void conv1k(const float* __restrict__ x, const float* __restrict__ wgt,
                       const float* __restrict__ bias, float* __restrict__ pmax,
                       float* __restrict__ pmin, float* __restrict__ stats, int t0) {
    int bb = blockIdx.x;
    int xt = bb % 3; int yt = (bb / 3) % 4; int t = (bb / 12) % 16; int n = bb / 192;
    int x0 = xt * 32, y0 = yt * 24;
    __shared__ float tile[9 * 936];           // [p=ci*3+kt][26 rows][36 (34 used)]
    __shared__ float wl[3456];                // [9p][32co][12 (9 used)] - b128 aligned
    __shared__ float sst[64];
    int tid = threadIdx.x;
    for (int i = tid; i < 3456; i += 256) {
        int idx = i % 12; int r = i / 12;
        int co = r & 31; int p = r >> 5;
        wl[i] = idx < 9 ? wgt[co * 81 + p * 9 + idx] : 0.f;
    }
    if (tid < 64) sst[tid] = 0.f;
    for (int i = tid; i < 7956; i += 256) {
        int p = i / 884; int rem = i % 884;
        int r = rem / 34, cl = rem % 34;
        int ci = p / 3, kt = p % 3;
        int lt = t + kt - 1;
        int yy = y0 + r - 1, xx = x0 + cl - 1;
        float v = 0.f;
        if (lt >= 0 && lt <= 15 && yy >= 0 && yy < 96 && xx >= 0 && xx < 96)
            v = x[((size_t)(n * 3 + ci) * 64 + (t0 + lt)) * 9216 + yy * 96 + cl + x0 - 1];
        tile[p * 936 + r * 36 + cl] = v;
    }
    __syncthreads();

    int cg = tid & 15;            // lane-fixed channel pair
    int co0 = cg * 2;
    float bv0 = bias[co0], bv1 = bias[co0 + 1];
    float ls0 = 0.f, lq0 = 0.f, ls1 = 0.f, lq1 = 0.f;
    size_t nt48 = (size_t)(n * 16 + t) * 48;

    #pragma unroll 1
    for (int rr = 0; rr < 3; ++rr) {
        int sp = rr * 16 + (tid >> 4);
        int tx = sp & 7, ty = sp >> 3;
        f32x4 a0_0 = (f32x4)bv0, a0_1 = (f32x4)bv0, a0_2 = (f32x4)bv0, a0_3 = (f32x4)bv0;
        f32x4 a1_0 = (f32x4)bv1, a1_1 = (f32x4)bv1, a1_2 = (f32x4)bv1, a1_3 = (f32x4)bv1;

        #pragma unroll 1
        for (int p = 0; p < 9; ++p) {
            const float* wpk = wl + ((p * 32 + co0) * 12);
            f32x4 wv0 = *(const f32x4*)(wpk);
            f32x4 wv1 = *(const f32x4*)(wpk + 4);
            f32x4 wv2 = *(const f32x4*)(wpk + 8);
            f32x4 wv3 = *(const f32x4*)(wpk + 12);
            f32x4 wv4 = *(const f32x4*)(wpk + 16);
            f32x4 wv5 = *(const f32x4*)(wpk + 20);
            float wa0 = wv0.x, wa1 = wv0.y, wa2 = wv0.z, wa3 = wv0.w;
            float wa4 = wv1.x, wa5 = wv1.y, wa6 = wv1.z, wa7 = wv1.w;
            float wa8 = wv2.x;
            float wb0 = wv3.x, wb1 = wv3.y, wb2 = wv3.z, wb3 = wv3.w;
            float wb4 = wv4.x, wb5 = wv4.y, wb6 = wv4.z, wb7 = wv4.w;
            float wb8 = wv5.x;
            const float* ip = tile + p * 936 + (ty * 4) * 36 + tx * 4;
            { C1LOADR(0) C1UPD0(0) }
            { C1LOADR(1) C1UPD0(1) C1UPD1(0) }
            { C1LOADR(2) C1UPD0(2) C1UPD1(1) C1UPD2(0) }
            { C1LOADR(3) C1UPD0(3) C1UPD1(2) C1UPD2(1) }
            { C1LOADR(4) C1UPD1(3) C1UPD2(2) }
            { C1LOADR(5) C1UPD2(3) }
        }

        // stats (full-res, pre-pool), accumulate in registers across rounds
        f32x4 s4 = a0_0 + a0_1 + a0_2 + a0_3;
        ls0 += s4.x + s4.y + s4.z + s4.w;
        f32x4 q4 = a0_0 * a0_0 + a0_1 * a0_1 + a0_2 * a0_2 + a0_3 * a0_3;
        lq0 += q4.x + q4.y + q4.z + q4.w;
        f32x4 s5 = a1_0 + a1_1 + a1_2 + a1_3;
        ls1 += s5.x + s5.y + s5.z + s5.w;
        f32x4 q5 = a1_0 * a1_0 + a1_1 * a1_1 + a1_2 * a1_2 + a1_3 * a1_3;
        lq1 += q5.x + q5.y + q5.z + q5.w;

        // 2x2 max/min pool in-register, direct coalesced stores
        f32x4 mx0a = vmax4(a0_0, a0_1), mx0b = vmax4(a0_2, a0_3);
        f32x4 mn0a = vmin4(a0_0, a0_1), mn0b = vmin4(a0_2, a0_3);
        f32x4 mx1a = vmax4(a1_0, a1_1), mx1b = vmax4(a1_2, a1_3);
        f32x4 mn1a = vmin4(a1_0, a1_1), mn1b = vmin4(a1_2, a1_3);
        size_t row0 = (nt48 + (size_t)(yt * 12 + ty * 2)) * 1536 + (size_t)(xt * 16 + tx * 2) * 32 + co0;
        size_t row1 = row0 + 1536;
        *(float2*)(pmax + row0)      = make_float2(fmaxf(mx0a.x, mx0a.y), fmaxf(mx1a.x, mx1a.y));
        *(float2*)(pmax + row0 + 32) = make_float2(fmaxf(mx0a.z, mx0a.w), fmaxf(mx1a.z, mx1a.w));
        *(float2*)(pmax + row1)      = make_float2(fmaxf(mx0b.x, mx0b.y), fmaxf(mx1b.x, mx1b.y));
        *(float2*)(pmax + row1 + 32) = make_float2(fmaxf(mx0b.z, mx0b.w), fmaxf(mx1b.z, mx1b.w));
        *(float2*)(pmin + row0)      = make_float2(fminf(mn0a.x, mn0a.y), fminf(mn1a.x, mn1a.y));
        *(float2*)(pmin + row0 + 32) = make_float2(fminf(mn0a.z, mn0a.w), fminf(mn1a.z, mn1a.w));
        *(float2*)(pmin + row1)      = make_float2(fminf(mn0b.x, mn0b.y), fminf(mn1b.x, mn1b.y));
        *(float2*)(pmin + row1 + 32) = make_float2(fminf(mn0b.z, mn0b.w), fminf(mn1b.z, mn1b.w));
    }

    // stats: reduce lanes sharing cg (stride 16/32 within wave), then LDS+global
    ls0 += __shfl_xor(ls0, 16, 64); ls0 += __shfl_xor(ls0, 32, 64);
    lq0 += __shfl_xor(lq0, 16, 64); lq0 += __shfl_xor(lq0, 32, 64);
    ls1 += __shfl_xor(ls1, 16, 64); ls1 += __shfl_xor(ls1, 32, 64);
    lq1 += __shfl_xor(lq1, 16, 64); lq1 += __shfl_xor(lq1, 32, 64);
    if ((tid & 63) < 16) {
        atomicAdd(&sst[co0 * 2], ls0);
        atomicAdd(&sst[co0 * 2 + 1], lq0);
        atomicAdd(&sst[co0 * 2 + 2], ls1);
        atomicAdd(&sst[co0 * 2 + 3], lq1);
    }
    __syncthreads();
    if (tid < 64) atomicAdd(&stats[tid], sst[tid]);
}

// -------- bnpool1b: pooled max/min -> BN affine + ReLU -> P2 hi/lo ----------
__global__ void bnpool1b(const float* __restrict__ pmax, const float* __restrict__ pmin,
                         const float* __restrict__ st, const float* __restrict__ gam,
                         const float* __restrict__ bet,
                         unsigned short* __restrict__ phi, unsigned short* __restrict__ plo) {
    int i = blockIdx.x * 256 + threadIdx.x;    // 589824 = 4*16*48*48*4
    int c8 = i & 3; int xo = (i >> 2) % 48; int yo = (i / 192) % 48;
    int t = (i / 9216) % 16; int n = i / 147456;
    size_t base = (((size_t)(n * 16 + t) * 48 + yo) * 48 + xo) * 32 + c8 * 8;
    union { unsigned short s[8]; uint4 v; } Uh, Ul;
    #pragma unroll
    for (int j = 0; j < 8; ++j) {
        int ch = c8 * 8 + j;
        float mean = st[ch * 2] * (1.f / 589824.f);
        float var  = st[ch * 2 + 1] * (1.f / 589824.f) - mean * mean;
        var = var < 0.f ? 0.f : var;
        float sc = gam[ch] / sqrtf(var + 1e-5f);
        float sh = bet[ch] - mean * sc;
        float pv = sc >= 0.f ? pmax[base + j] : pmin[base + j];
        float v = fmaxf(sc * pv + sh, 0.f);
        Uh.s[j] = f2bf(v);
        Ul.s[j] = f2bf(v - bf2f(Uh.s[j]));
    }
    size_t off = ((((size_t)n * 18 + t + 1) * 50 + yo + 1) * 52 + (xo + 1)) * 32 + c8 * 8;
    *(uint4*)(phi + off) = Uh.v;
    *(uint4*)(plo + off) = Ul.v;
}

// -------- conv2: 2-row x 32-co waves. Padded LDS [12][52][40] (r14, stride
// 80B, conflict-free). Per step: 4 weight loads (was 8), 12 B ds_reads.
// MFMA chain per output unchanged -> conv outputs bit-identical. ------------
__launch_bounds__(256, 3)
__global__ void conv2k(const unsigned short* __restrict__ phi, const unsigned short* __restrict__ plo,
                       const unsigned short* __restrict__ w2p, const float* __restrict__ bias,
                       float* __restrict__ out, float* __restrict__ st) {
    __shared__ unsigned short tin[12 * 52 * 40];      // 24960 shorts = 49920 B
    float (*sred)[32] = (float (*)[32])(tin);          // alias: epilogue only
    float (*qred)[32] = (float (*)[32])(tin + 256);
    // XCD swizzle: 768 = 8 chunks x 96; chunk = (n, t-half).
    int b = blockIdx.x;
    int k8 = b & 7, i96 = b >> 3;
    int n = k8 >> 1, th = k8 & 1;
    int tt = i96 / 12; int y0 = (i96 - tt * 12) * 4;
    int t = th * 8 + tt;
    int w = threadIdx.x >> 6, lane = threadIdx.x & 63;
    int c = lane & 15, q = lane >> 4;
    int lrow = (w & 1) * 2, h2 = w >> 1;

    f32x4 acc[2][2][3];                                // [rr][mb'][xt]
    #pragma unroll
    for (int i = 0; i < 2; ++i)
        #pragma unroll
        for (int j = 0; j < 2; ++j)
            #pragma unroll
            for (int k = 0; k < 3; ++k) acc[i][j][k] = (f32x4)0.f;

    const int loff = h2 * 1024 + c * 32 + q * 8;       // weight lane offset (shorts)
    int tbo[2][3];                                     // B base offsets (shorts)
    #pragma unroll
    for (int rr = 0; rr < 2; ++rr)
        #pragma unroll
        for (int xt = 0; xt < 3; ++xt)
            tbo[rr][xt] = ((lrow + rr) * 52 + xt * 16 + c) * 40 + q * 8;

    #pragma unroll 1
    for (int kt = 0; kt < 3; ++kt) {
        const unsigned short* srch = phi + (size_t)(n * 18 + t + kt) * (50 * 52 * 32);
        const unsigned short* srcl = plo + (size_t)(n * 18 + t + kt) * (50 * 52 * 32);
        const unsigned short* wkt = w2p + kt * 36864;   // uniform (SGPR)
        __syncthreads();
        for (int i = threadIdx.x; i < 2496; i += 256) { // 12*52*4 16B-chunks
            int g = i & 3; int xx = (i >> 2) % 52; int rh = (i >> 2) / 52;
            int row = rh % 6; int h = rh / 6;
            const unsigned short* src = (h ? srcl : srch) + (size_t)(y0 + row) * 1664 + xx * 32 + g * 8;
            *(uint4*)(tin + (rh * 52 + xx) * 40 + (g << 3)) = *(const uint4*)src;
        }
        __syncthreads();
        #pragma unroll
        for (int ky = 0; ky < 3; ++ky) {
            #pragma unroll
            for (int kx = 0; kx < 3; ++kx) {
                const unsigned short* wb = wkt + (ky * 3 + kx) * 4096 + loff;
                short8 a0 = *(const short8*)(wb);
                short8 a1 = *(const short8*)(wb + 512);
                short8 l0 = *(const short8*)(wb + 2048);
                short8 l1 = *(const short8*)(wb + 2560);
                int off = (ky * 52 + kx) * 40;          // compile-time per step
                #pragma unroll
                for (int rr = 0; rr < 2; ++rr) {
                    short8 bh0 = *(const short8*)(tin + tbo[rr][0] + off);
                    short8 bl0 = *(const short8*)(tin + tbo[rr][0] + off + 12480);
                    short8 bh1 = *(const short8*)(tin + tbo[rr][1] + off);
                    short8 bl1 = *(const short8*)(tin + tbo[rr][1] + off + 12480);
                    short8 bh2 = *(const short8*)(tin + tbo[rr][2] + off);
                    short8 bl2 = *(const short8*)(tin + tbo[rr][2] + off + 12480);
                    MF(acc[rr][0][0], a0, bh0); MF(acc[rr][0][0], a0, bl0); MF(acc[rr][0][0], l0, bh0);
                    MF(acc[rr][0][1], a0, bh1); MF(acc[rr][0][1], a0, bl1); MF(acc[rr][0][1], l0, bh1);
                    MF(acc[rr][0][2], a0, bh2); MF(acc[rr][0][2], a0, bl2); MF(acc[rr][0][2], l0, bh2);
                    MF(acc[rr][1][0], a1, bh0); MF(acc[rr][1][0], a1, bl0); MF(acc[rr][1][0], l1, bh0);
                    MF(acc[rr][1][1], a1, bh1); MF(acc[rr][1][1], a1, bl1); MF(acc[rr][1][1], l1, bh1);
                    MF(acc[rr][1][2], a1, bh2); MF(acc[rr][1][2], a1, bl2); MF(acc[rr][1][2], l1, bh2);
                }
            }
        }
    }
    __syncthreads();        // fence: tin reads done before sred/qred alias writes
    #pragma unroll
    for (int mbp = 0; mbp < 2; ++mbp) {
        f32x4 bv = *(const f32x4*)(bias + h2 * 32 + mbp * 16 + q * 4);
        float s0 = 0.f, s1 = 0.f, s2 = 0.f, s3 = 0.f;
        float p0 = 0.f, p1 = 0.f, p2 = 0.f, p3 = 0.f;
        #pragma unroll
        for (int rr = 0; rr < 2; ++rr) {
            int y = y0 + lrow + rr;
            float* ob = out + (((size_t)(n * 16 + t) * 48) + y) * (48 * 64) + h2 * 32 + mbp * 16 + q * 4;
            #pragma unroll
            for (int xt = 0; xt < 3; ++xt) {
                f32x4 v = acc[rr][mbp][xt] + bv;
                *(f32x4*)(ob + (xt * 16 + c) * 64) = v;
                s0 += v.x; s1 += v.y; s2 += v.z; s3 += v.w;
                p0 += v.x * v.x; p1 += v.y * v.y; p2 += v.z * v.z; p3 += v.w * v.w;
            }
        }
        float sv[4] = {s0, s1, s2, s3}, qv[4] = {p0, p1, p2, p3};
        #pragma unroll
        for (int r = 0; r < 4; ++r) {
            float s = sv[r], q2 = qv[r];
            #pragma unroll
            for (int m = 1; m < 16; m <<= 1) { s += __shfl_xor(s, m, 64); q2 += __shfl_xor(q2, m, 64); }
            if (c == 0) { sred[w][mbp * 16 + q * 4 + r] = s; qred[w][mbp * 16 + q * 4 + r] = q2; }
        }
    }
    __syncthreads();
    if (threadIdx.x < 64) {
        int h = threadIdx.x >> 5, loc = threadIdx.x & 31;
        float s = sred[2 * h][loc] + sred[2 * h + 1][loc];
        float q2 = qred[2 * h][loc] + qred[2 * h + 1][loc];
        atomicAdd(&st[threadIdx.x * 2], s);
        atomicAdd(&st[threadIdx.x * 2 + 1], q2);
    }
}

// -------- bnpool2: conv2 out chan-last -> P3 [n][18][26][34][64] hi/lo ------
__global__ void bnpool2k(const float* __restrict__ cin, const float* __restrict__ st,
                         const float* __restrict__ gam, const float* __restrict__ bet,
                         unsigned short* __restrict__ phi, unsigned short* __restrict__ plo) {
    int i = blockIdx.x * 256 + threadIdx.x;    // 509184
    if (i >= 509184) return;
    int oc = i & 7; int xp = (i >> 3) % 34; int yp = (i / 272) % 26;
    int tp = (i / 7072) % 18; int n = i / 127296;
    union { unsigned short s[8]; uint4 v; } Uh, Ul;
    if (tp >= 1 && tp <= 16 && yp >= 1 && yp <= 24 && xp >= 1 && xp <= 24) {
        int t = tp - 1, yo = yp - 1, xo = xp - 1;
        const float* b0 = cin + ((((size_t)(n * 16 + t) * 48) + 2 * yo) * 48 + 2 * xo) * 64 + oc * 8;
        #pragma unroll
        for (int j = 0; j < 8; ++j) {
            int ch = oc * 8 + j;
            float mean = st[ch * 2] * (1.f / 147456.f);
            float var  = st[ch * 2 + 1] * (1.f / 147456.f) - mean * mean;
            var = var < 0.f ? 0.f : var;
            float sc = gam[ch] / sqrtf(var + 1e-5f);
            float sh = bet[ch] - mean * sc;
            float a  = b0[j] * sc + sh;
            float bb = b0[64 + j] * sc + sh;
            float c2 = b0[3072 + j] * sc + sh;
            float d  = b0[3136 + j] * sc + sh;
            float v = fmaxf(fmaxf(fmaxf(a, bb), fmaxf(c2, d)), 0.f);
            Uh.s[j] = f2bf(v);
            Ul.s[j] = f2bf(v - bf2f(Uh.s[j]));
        }
    } else {
        Uh.v = make_uint4(0, 0, 0, 0);
        Ul.v = make_uint4(0, 0, 0, 0);
    }
    size_t off = ((((size_t)n * 18 + tp) * 26 + yp) * 34 + xp) * 64 + oc * 8;
    *(uint4*)(phi + off) = Uh.v;
    *(uint4*)(plo + off) = Ul.v;
}

// -------- conv3: 2-row x 32-co waves. r13 XOR LDS layout (39936B, proven
// best). Per step: 4 weight loads (was 8), 8 B ds_reads. MFMA chain per
// output unchanged -> conv outputs bit-identical. ---------------------------
__launch_bounds__(256, 3)
__global__ void conv3k(const unsigned short* __restrict__ phi, const unsigned short* __restrict__ plo,
                       const unsigned short* __restrict__ w3p, const float* __restrict__ bias,
                       float* __restrict__ out, float* __restrict__ st) {
    __shared__ unsigned short tin[12 * 26 * 64];      // 19968 shorts = 39936 B
    float (*sred)[32] = (float (*)[32])(tin);          // alias: epilogue only
    float (*qred)[32] = (float (*)[32])(tin + 256);
    // XCD swizzle: 768 = 8 chunks x 96; chunk = (n, t-half), both cg inside.
    int b = blockIdx.x;
    int k8 = b & 7, i96 = b >> 3;
    int n = k8 >> 1, th = k8 & 1;
    int cg = i96 / 48; int r48 = i96 - cg * 48;
    int tt = r48 / 6;  int y0 = (r48 - tt * 6) * 4;
    int t = th * 8 + tt;
    int w = threadIdx.x >> 6, lane = threadIdx.x & 63;
    int c = lane & 15, q = lane >> 4;
    int lrow = (w & 1) * 2, h2 = w >> 1;

    f32x4 acc[2][2][2];                                // [rr][mb'][xt]
    #pragma unroll
    for (int i = 0; i < 2; ++i)
        #pragma unroll
        for (int j = 0; j < 2; ++j) { acc[i][j][0] = (f32x4)0.f; acc[i][j][1] = (f32x4)0.f; }

    const unsigned short* wsrc = w3p + (size_t)cg * 221184 + h2 * 1024 + c * 32 + q * 8;

    #pragma unroll 1
    for (int kt = 0; kt < 3; ++kt) {
        const unsigned short* srch = phi + (size_t)(n * 18 + t + kt) * (26 * 34 * 64);
        const unsigned short* srcl = plo + (size_t)(n * 18 + t + kt) * (26 * 34 * 64);
        const unsigned short* wkt = wsrc + kt * 73728;
        __syncthreads();
        for (int i = threadIdx.x; i < 2496; i += 256) {     // 12*26*8 16B-chunks
            int g = i & 7; int xx = (i >> 3) % 26; int rh = (i >> 3) / 26;
            int row = rh % 6; int h = rh / 6;
            const unsigned short* src = (h ? srcl : srch) + (size_t)(y0 + row) * 2176 + xx * 64 + g * 8;
            *(uint4*)(tin + ((rh * 26 + xx) << 6) + ((g ^ (xx & 7)) << 3)) = *(const uint4*)src;
        }
        __syncthreads();
        #pragma unroll
        for (int ky = 0; ky < 3; ++ky) {
            #pragma unroll
            for (int kx = 0; kx < 3; ++kx) {
                #pragma unroll
                for (int kc = 0; kc < 2; ++kc) {
                    const unsigned short* wb = wkt + ky * 24576 + kx * 8192 + kc * 2048;
                    short8 a0 = *(const short8*)(wb);
                    short8 a1 = *(const short8*)(wb + 512);
                    short8 l0 = *(const short8*)(wb + 4096);
                    short8 l1 = *(const short8*)(wb + 4608);
                    int x0 = kx + c;
                    int x1t = 16 + kx + c;
                    int x1 = x1t > 25 ? 25 : x1t;   // c>=8 @ xt=1: discarded cols, finite junk
                    int so0 = ((kc * 4 + q) ^ (x0 & 7)) << 3;
                    int so1 = ((kc * 4 + q) ^ (x1 & 7)) << 3;
                    #pragma unroll
                    for (int rr = 0; rr < 2; ++rr) {
                        int row = lrow + rr + ky;
                        short8 bh0 = *(const short8*)(tin + ((row * 26 + x0) << 6) + so0);
                        short8 bl0 = *(const short8*)(tin + (((6 + row) * 26 + x0) << 6) + so0);
                        short8 bh1 = *(const short8*)(tin + ((row * 26 + x1) << 6) + so1);
                        short8 bl1 = *(const short8*)(tin + (((6 + row) * 26 + x1) << 6) + so1);
                        MF(acc[rr][0][0], a0, bh0); MF(acc[rr][0][0], a0, bl0); MF(acc[rr][0][0], l0, bh0);
                        MF(acc[rr][0][1], a0, bh1); MF(acc[rr][0][1], a0, bl1); MF(acc[rr][0][1], l0, bh1);
                        MF(acc[rr][1][0], a1, bh0); MF(acc[rr][1][0], a1, bl0); MF(acc[rr][1][0], l1, bh0);
                        MF(acc[rr][1][1], a1, bh1); MF(acc[rr][1][1], a1, bl1); MF(acc[rr][1][1], l1, bh1);
                    }
                }
            }
        }
    }
    __syncthreads();        // fence: tin reads done before sred/qred alias writes
    #pragma unroll
    for (int mbp = 0; mbp < 2; ++mbp) {
        f32x4 bv = *(const f32x4*)(bias + cg * 64 + h2 * 32 + mbp * 16 + q * 4);
        float s0 = 0.f, s1 = 0.f, s2 = 0.f, s3 = 0.f;
        float p0 = 0.f, p1 = 0.f, p2 = 0.f, p3 = 0.f;
        #pragma unroll
        for (int rr = 0; rr < 2; ++rr) {
            int y = y0 + lrow + rr;
            float* ob = out + (((size_t)(n * 16 + t) * 24) + y) * (24 * 128) + cg * 64 + h2 * 32 + mbp * 16 + q * 4;
            f32x4 v0 = acc[rr][mbp][0] + bv;
            f32x4 v1 = acc[rr][mbp][1] + bv;
            *(f32x4*)(ob + c * 128) = v0;
            if (c < 8) *(f32x4*)(ob + (16 + c) * 128) = v1;
            float m = c < 8 ? 1.f : 0.f;
            s0 += v0.x + m * v1.x; s1 += v0.y + m * v1.y; s2 += v0.z + m * v1.z; s3 += v0.w + m * v1.w;
            p0 += v0.x * v0.x + m * v1.x * v1.x; p1 += v0.y * v0.y + m * v1.y * v1.y;
            p2 += v0.z * v0.z + m * v1.z * v1.z; p3 += v0.w * v0.w + m * v1.w * v1.w;
        }
        float sv[4] = {s0, s1, s2, s3}, qv[4] = {p0, p1, p2, p3};
        #pragma unroll
        for (int r = 0; r < 4; ++r) {
            float s = sv[r], q2 = qv[r];
            #pragma unroll
            for (int m = 1; m < 16; m <<= 1) { s += __shfl_xor(s, m, 64); q2 += __shfl_xor(q2, m, 64); }
            if (c == 0) { sred[w][mbp * 16 + q * 4 + r] = s; qred[w][mbp * 16 + q * 4 + r] = q2; }
        }
    }
    __syncthreads();
    if (threadIdx.x < 64) {
        int h = threadIdx.x >> 5, loc = threadIdx.x & 31;
        int co = cg * 64 + threadIdx.x;
        float s = sred[2 * h][loc] + sred[2 * h + 1][loc];
        float q2 = qred[2 * h][loc] + qred[2 * h + 1][loc];
        atomicAdd(&st[co * 2], s);
        atomicAdd(&st[co * 2 + 1], q2);
    }
}

// -------- BN + ReLU + avgpool 6x6 (chan-last in) -> enc ---------------------
__global__ void bnavgk(const float* __restrict__ x, const float* __restrict__ st,
                       const float* __restrict__ gam, const float* __restrict__ bet,
                       float* __restrict__ enc) {
    int i = blockIdx.x * 256 + threadIdx.x;    // 131072
    int c = i & 127; int xo = (i >> 7) & 3; int yo = (i >> 9) & 3;
    int t = (i >> 11) & 15; int n = i >> 15;
    float mean = st[c * 2] * (1.f / 36864.f);
    float var  = st[c * 2 + 1] * (1.f / 36864.f) - mean * mean;
    var = var < 0.f ? 0.f : var;
    float sc = gam[c] / sqrtf(var + 1e-5f);
    float sh = bet[c] - mean * sc;
    const float* base = x + ((((size_t)(n * 16 + t) * 24) + yo * 6) * 24 + xo * 6) * 128 + c;
    float s = 0.f;
    #pragma unroll
    for (int wy = 0; wy < 6; ++wy)
        #pragma unroll
        for (int wx = 0; wx < 6; ++wx)
            s += fmaxf(base[(wy * 24 + wx) * 128] * sc + sh, 0.f);
    enc[(size_t)n * 32768 + (size_t)c * 256 + t * 16 + yo * 4 + xo] = s * (1.f / 36.f);
}

// -------- weight prepack kernels -------------------------------------------
__global__ void prep2k(const float* __restrict__ c2w, unsigned short* __restrict__ w2p) {
    int i = blockIdx.x * 256 + threadIdx.x;    // 110592
    if (i >= 110592) return;
    int ci = i & 31; int co = (i >> 5) & 63; int h = (i >> 11) & 1;
    int o = (i >> 12) % 9; int kt = i / 36864;
    int ky = o / 3, kx = o % 3;
    float w = c2w[(((size_t)(co * 32 + ci) * 3 + kt) * 3 + ky) * 3 + kx];
    unsigned short hi = f2bf(w);
    w2p[i] = h ? f2bf(w - bf2f(hi)) : hi;
}
__global__ void prep3k(const float* __restrict__ c3w, unsigned short* __restrict__ w3p) {
    int i = blockIdx.x * 256 + threadIdx.x;    // 442368
    if (i >= 442368) return;
    int cil = i & 31; int cop = (i >> 5) & 63; int kc = (i >> 11) & 1; int h = (i >> 12) & 1;
    int kx = (i >> 13) % 3; int ky = (i / 24576) % 3; int kt = (i / 73728) % 3; int cg = i / 221184;
    int ci = kc * 32 + cil; int co = cg * 64 + cop;
    float w = c3w[(((size_t)(co * 64 + ci) * 3 + kt) * 3 + ky) * 3 + kx];
    unsigned short hi = f2bf(w);
    w3p[i] = h ? f2bf(w - bf2f(hi)) : hi;
}
__global__ void prepwhhk(const float* __restrict__ whh, float* __restrict__ wt) {
    int i = blockIdx.x * 256 + threadIdx.x;    // 196608
    int g = i % 768, k = i / 768;
    wt[i] = whh[(size_t)g * 256 + k];
}

// -------- codebook transpose: cb[8192][256] -> cbT[256][8192] ---------------
__global__ void transck(const float* __restrict__ cb, float* __restrict__ cbT) {
    __shared__ float t[32][33];
    int bx = blockIdx.x & 255;
    int by = blockIdx.x >> 8;
    int ld = threadIdx.x & 31, lk = threadIdx.x >> 5;
    #pragma unroll
    for (int i = 0; i < 4; ++i) {
        int kl = lk + i * 8;
        t[kl][ld] = cb[(size_t)(bx * 32 + kl) * 256 + by * 32 + ld];
    }
    __syncthreads();
    #pragma unroll
    for (int i = 0; i < 4; ++i) {
        int dl = lk + i * 8;
        cbT[(size_t)(by * 32 + dl) * 8192 + bx * 32 + ld] = t[ld][dl];
    }
}

// -------- code norms in fp64 (ascending d, matches reference order) ---------
__global__ void cnormk(const float* __restrict__ cbT, double* __restrict__ cn2) {
    int k = blockIdx.x * 256 + threadIdx.x;    // 8192
    double s = 0.0;
    for (int d = 0; d < 256; ++d) {
        double c = (double)cbT[(size_t)d * 8192 + k];
        s += c * c;
    }
    cn2[k] = s;
}

// -------- proj init: feat = pb broadcast ------------------------------------
__global__ void projinitk(const float* __restrict__ pb, float* __restrict__ feat) {
    int i = blockIdx.x * 256 + threadIdx.x;    // 7168
    feat[i] = pb[i & 255];
}

// -------- proj, d-tiled: 256 blocks = 32 d-groups x 8 k-chunks. Each block
// computes 8 d for all 28 rows -> enc traffic /8 (940MB -> 117MB). ----------
__global__ void projk(const float* __restrict__ enc, const float* __restrict__ pw,
                      float* __restrict__ feat) {
    int dg = blockIdx.x >> 3, ch = blockIdx.x & 7;     // 256 blocks
    int dl = threadIdx.x >> 5, kk = threadIdx.x & 31;  // 8 d x 32 k-lanes
    int d = dg * 8 + dl;
    int k0 = ch * 4096 + kk * 4;
    const float* wrow = pw + (size_t)d * 32768 + k0;
    const float* ep = enc + k0;
    float acc[28];
    #pragma unroll
    for (int e = 0; e < 28; ++e) acc[e] = 0.f;
    #pragma unroll 1
    for (int i = 0; i < 32; ++i) {
        f32x4 wv = *(const f32x4*)(wrow + i * 128);
        #pragma unroll
        for (int e = 0; e < 28; ++e) {
            f32x4 ev = *(const f32x4*)(ep + (size_t)e * 32768 + i * 128);
            acc[e] += wv.x * ev.x + wv.y * ev.y + wv.z * ev.z + wv.w * ev.w;
        }
    }
    #pragma unroll
    for (int e = 0; e < 28; ++e) {
        float v = acc[e];
        v += __shfl_xor(v, 1, 64);  v += __shfl_xor(v, 2, 64);
        v += __shfl_xor(v, 4, 64);  v += __shfl_xor(v, 8, 64);
        v += __shfl_xor(v, 16, 64);
        if (kk == 0) atomicAdd(&feat[(size_t)((e & 3) * 7 + (e >> 2)) * 256 + d], v);
    }
}

// -------- VQ: argmin over transposed codebook, fp64, 896 blocks -------------
__global__ void quantk(const float* __restrict__ feat, const float* __restrict__ cbT,
                       const double* __restrict__ cn2, unsigned long long* __restrict__ best) {
    int kc = blockIdx.x & 31, r = blockIdx.x >> 5;     // 896 = 32kc * 28r
    int k = kc * 256 + threadIdx.x;
    __shared__ float fs[256];
    fs[threadIdx.x] = feat[(size_t)r * 256 + threadIdx.x];
    __syncthreads();
    double dot = 0.0;
    for (int d = 0; d < 256; ++d)
        dot += (double)cbT[(size_t)d * 8192 + k] * (double)fs[d];
    float s = (float)(cn2[k] - 2.0 * dot);
    unsigned int bits = __float_as_uint(s);
    unsigned int key = (bits & 0x80000000u) ? ~bits : (bits | 0x80000000u);
    unsigned long long p = ((unsigned long long)key << 32) | (unsigned int)k;
    #pragma unroll
    for (int o = 32; o > 0; o >>= 1) {
        unsigned long long qv = __shfl_down(p, o, 64);
        if (qv < p) p = qv;
    }
    if ((threadIdx.x & 63) == 0) atomicMin(&best[r], p);
}

__global__ void gatherk(const unsigned long long* __restrict__ best,
                        const float* __restrict__ feat, const float* __restrict__ cb,
                        float* __restrict__ dout, float* __restrict__ quant,
                        float* __restrict__ acc) {
    int r = blockIdx.x;
    int d = threadIdx.x;
    int idx = (int)(best[r] & 0xFFFFFFFFull);
    float q = cb[(size_t)idx * 256 + d];
    quant[r * 256 + d] = q;
    dout[28 + r * 256 + d] = q;
    if (d == 0) dout[r] = (float)idx;
    float df = feat[r * 256 + d] - q;
    float v = df * df;
    #pragma unroll
    for (int o = 32; o > 0; o >>= 1) v += __shfl_down(v, o, 64);
    if ((d & 63) == 0) atomicAdd(&acc[0], v);
}

__global__ void gxk(const float* __restrict__ quant, const float* __restrict__ wih,
                    const float* __restrict__ bih, float* __restrict__ gx) {
    int o = blockIdx.x * 256 + threadIdx.x;
    int g = o % 768; int t = (o / 768) % 6; int n = o / (768 * 6);
    const float* q = quant + (size_t)(n * 7 + t) * 256;
    const float* w = wih + (size_t)g * 256;
    float s = bih[g];
    #pragma unroll 4
    for (int d = 0; d < 256; ++d) s += q[d] * w[d];
    gx[o] = s;
}

// -------- all 6 GRU steps in one kernel (block = batch b) -------------------
__global__ void gru_allk(const float* __restrict__ gx, const float* __restrict__ wt,
                         const float* __restrict__ bhh, const float* __restrict__ feat,
                         float* __restrict__ acc) {
    int b = blockIdx.x;        // 4
    int d = threadIdx.x;       // 256
    __shared__ float hs[256];
    hs[d] = 0.f;
    __syncthreads();
    float ctx = 0.f;
    for (int t = 0; t < 6; ++t) {
        float g0 = bhh[d], g1 = bhh[256 + d], g2 = bhh[512 + d];
        #pragma unroll 4
        for (int k = 0; k < 256; ++k) {
            float hv = hs[k];
            const float* wr = wt + (size_t)k * 768;
            g0 += wr[d] * hv; g1 += wr[256 + d] * hv; g2 += wr[512 + d] * hv;
        }
        const float* gxr = gx + (size_t)(b * 6 + t) * 768;
        float xr = gxr[d], xz = gxr[256 + d], xn = gxr[512 + d];
        float rr = 1.f / (1.f + expf(-(xr + g0)));
        float zz = 1.f / (1.f + expf(-(xz + g1)));
        float nn = tanhf(xn + rr * g2);
        float h2 = (1.f - zz) * nn + zz * hs[d];
        __syncthreads();
        hs[d] = h2;
        __syncthreads();
        float df = h2 - feat[(size_t)(b * 7 + t + 1) * 256 + d];
        ctx += df * df;
    }
    #pragma unroll
    for (int o = 32; o > 0; o >>= 1) ctx += __shfl_down(ctx, o, 64);
    if ((d & 63) == 0) atomicAdd(&acc[1], ctx);
}

__global__ void fink(const float* __restrict__ acc, float* __restrict__ dout) {
    float comm = acc[0] / 7168.f;
    float ctx  = acc[1] / 6144.f;
    dout[7196] = comm;
    dout[7197] = comm;
    dout[7198] = ctx;
    dout[7199] = comm + 0.25f * comm + 0.1f * ctx;
}

// ---------------------------------------------------------------------------
extern "C" void kernel_launch(void* const* d_in, const int* in_sizes, int n_in,
                              void* d_out, int out_size, void* d_ws, size_t ws_size,
                              hipStream_t stream) {
    (void)in_sizes; (void)n_in; (void)out_size; (void)ws_size;
    const float* x    = (const float*)d_in[0];
    const float* c1w  = (const float*)d_in[1];
    const float* c1b  = (const float*)d_in[2];
    const float* bn1g = (const float*)d_in[3];
    const float* bn1b = (const float*)d_in[4];
    const float* c2w  = (const float*)d_in[5];
    const float* c2b  = (const float*)d_in[6];
    const float* bn2g = (const float*)d_in[7];
    const float* bn2b = (const float*)d_in[8];
    const float* c3w  = (const float*)d_in[9];
    const float* c3b  = (const float*)d_in[10];
    const float* bn3g = (const float*)d_in[11];
    const float* bn3b = (const float*)d_in[12];
    const float* pw   = (const float*)d_in[13];
    const float* pb   = (const float*)d_in[14];
    const float* cb   = (const float*)d_in[15];
    const float* wih  = (const float*)d_in[16];
    const float* whh  = (const float*)d_in[17];
    const float* bih  = (const float*)d_in[18];
    const float* bhh  = (const float*)d_in[19];
    float* out = (float*)d_out;

    // ---- workspace layout (bytes) ----
    char* w = (char*)d_ws;
    float* A  = (float*)w;                         w += 75497472;   // conv2/3 outs; pmax/pmin + cbT alias
    float* PMAX = A;                                                // 18.87 MB (alias)
    float* PMIN = A + 4718592;                                      // 18.87 MB (alias)
    float* cbT = A;                                                 // 8 MB (alias, post-loop)
    double* cn2 = (double*)((char*)A + 8388608);                    // 64 KB (alias, post-loop)
    char*  SH = w;                                 w += 16293888;   // P3 hi/lo
    unsigned short* P3h = (unsigned short*)SH;
    unsigned short* P3l = (unsigned short*)(SH + 8146944);
    unsigned short* P2h = (unsigned short*)w;      w += 11980800;
    unsigned short* P2l = (unsigned short*)w;      w += 11980800;
    unsigned short* W2P = (unsigned short*)w;      w += 221184;
    unsigned short* W3P = (unsigned short*)w;      w += 884736;
    float* WT    = (float*)w;                      w += 786432;     // whh transposed [256][768]
    float* enc   = (float*)w;                      w += 3670016;
    float* feat  = (float*)w;                      w += 28672;
    float* quant = (float*)w;                      w += 28672;
    float* gx    = (float*)w;                      w += 73728;
    float* statsA = (float*)w;                     w += 21504;      // 21 x 256 floats
    float* acc    = (float*)w;                     w += 16;
    unsigned long long* best = (unsigned long long*)w;  w += 224;

    // ---- per-launch init ----
    hipMemsetAsync(P2h, 0, 11980800 * 2, stream);                  // P2 hi+lo pads
    hipMemsetAsync(statsA, 0, 21504 + 16, stream);                 // stats + acc
    hipMemsetAsync(best, 0xFF, 224, stream);
    prep2k<<<432, 256, 0, stream>>>(c2w, W2P);
    prep3k<<<1728, 256, 0, stream>>>(c3w, W3P);
    prepwhhk<<<768, 256, 0, stream>>>(whh, WT);

    for (int l = 0; l < 7; ++l) {
        float* st1 = statsA + (l * 3 + 0) * 256;
        float* st2 = statsA + (l * 3 + 1) * 256;
        float* st3 = statsA + (l * 3 + 2) * 256;
        conv1k<<<768, 256, 0, stream>>>(x, c1w, c1b, PMAX, PMIN, st1, l * 8);
        bnpool1b<<<2304, 256, 0, stream>>>(PMAX, PMIN, st1, bn1g, bn1b, P2h, P2l);
        conv2k<<<768, 256, 0, stream>>>(P2h, P2l, W2P, c2b, A, st2);
        bnpool2k<<<1989, 256, 0, stream>>>(A, st2, bn2g, bn2b, P3h, P3l);
        conv3k<<<768, 256, 0, stream>>>(P3h, P3l, W3P, c3b, A, st3);
        bnavgk<<<512, 256, 0, stream>>>(A, st3, bn3g, bn3b, enc + (size_t)l * 131072);
    }

    // A is free now: build transposed codebook + norms in its space
    transck<<<2048, 256, 0, stream>>>(cb, cbT);
    cnormk<<<32, 256, 0, stream>>>(cbT, cn2);
    projinitk<<<28, 256, 0, stream>>>(pb, feat);
    projk<<<256, 256, 0, stream>>>(enc, pw, feat);
    quantk<<<896, 256, 0, stream>>>(feat, cbT, cn2, best);
    gatherk<<<28, 256, 0, stream>>>(best, feat, cb, out, quant, acc);
    gxk<<<72, 256, 0, stream>>>(quant, wih, bih, gx);
    gru_allk<<<4, 256, 0, stream>>>(gx, WT, bhh, feat, acc);
    fink<<<1, 1, 0, stream>>>(acc, out);
}

// Round 8
// 2329.784 us; speedup vs baseline: 1.0266x; 1.0266x over previous
//
#include <hip/hip_runtime.h>
#include <math.h>

// ---------------------------------------------------------------------------
// VQSign r16: surgical revert of r15's projk regression. r15's d-tiled projk
// launched 256 blocks = 1 block/CU (occupancy 11%, 0 MFMA, VALU 6.8%) ->
// latency-bound at 155.8us, +105us vs the old 2048-block version; its "enc
// re-read" motivation was bogus (enc = 3.67MB, fully L2/L3-resident). The
// r15 conv remap WORKED: conv3k dropped out of the top-5 (<155us) and the
// e2e math shows conv2k+conv3k netted ~-36us. r16 = r15 convs unchanged +
// r14's proven projk (2048 blocks = 256 d x 8 k-chunks, 8 blocks/CU,
// absmax-0-proven summation order). Single-variable change.
// ---------------------------------------------------------------------------

typedef __attribute__((ext_vector_type(8))) short short8;
typedef __attribute__((ext_vector_type(4))) float f32x4;

__device__ inline unsigned short f2bf(float x) {
    unsigned int u = __float_as_uint(x);
    u += 0x7FFFu + ((u >> 16) & 1u);          // RNE
    return (unsigned short)(u >> 16);
}
__device__ inline float bf2f(unsigned short h) {
    return __uint_as_float(((unsigned int)h) << 16);
}
__device__ inline f32x4 vmax4(f32x4 a, f32x4 b) {
    return (f32x4){fmaxf(a.x, b.x), fmaxf(a.y, b.y), fmaxf(a.z, b.z), fmaxf(a.w, b.w)};
}
__device__ inline f32x4 vmin4(f32x4 a, f32x4 b) {
    return (f32x4){fminf(a.x, b.x), fminf(a.y, b.y), fminf(a.z, b.z), fminf(a.w, b.w)};
}

#define MF(d, a, b) d = __builtin_amdgcn_mfma_f32_16x16x32_bf16(a, b, d, 0, 0, 0)

// ---------------- conv1: fp32, LDS tile, pooled max/min chan-last out -------
#define C1LOADR(J) \
    f32x4 u = *(const f32x4*)(ip + (J) * 36); \
    f32x4 w4 = *(const f32x4*)(ip + (J) * 36 + 4); \
    f32x4 sA = u; \
    f32x4 sB = __builtin_shufflevector(u, w4, 1, 2, 3, 4); \
    f32x4 sC = __builtin_shufflevector(u, w4, 2, 3, 4, 5);
#define C1UPD0(I) a0_##I += wa0 * sA + wa1 * sB + wa2 * sC; a1_##I += wb0 * sA + wb1 * sB + wb2 * sC;
#define C1UPD1(I) a0_##I += wa3 * sA + wa4 * sB + wa5 * sC; a1_##I += wb3 * sA + wb4 * sB + wb5 * sC;
#define C1UPD2(I) a0_##I += wa6 * sA + wa7 * sB + wa8 * sC; a1_##I += wb6 * sA + wb7 * sB + wb8 * sC;

__launch_bounds__(256, 3)
__global__ void conv1k(const float* __restrict__ x, const float* __restrict__ wgt,
                       const float* __restrict__ bias, float* __restrict__ pmax,
                       float* __restrict__ pmin, float* __restrict__ stats, int t0) {
    int bb = blockIdx.x;
    int xt = bb % 3; int yt = (bb / 3) % 4; int t = (bb / 12) % 16; int n = bb / 192;
    int x0 = xt * 32, y0 = yt * 24;
    __shared__ float tile[9 * 936];           // [p=ci*3+kt][26 rows][36 (34 used)]
    __shared__ float wl[3456];                // [9p][32co][12 (9 used)] - b128 aligned
    __shared__ float sst[64];
    int tid = threadIdx.x;
    for (int i = tid; i < 3456; i += 256) {
        int idx = i % 12; int r = i / 12;
        int co = r & 31; int p = r >> 5;
        wl[i] = idx < 9 ? wgt[co * 81 + p * 9 + idx] : 0.f;
    }
    if (tid < 64) sst[tid] = 0.f;
    for (int i = tid; i < 7956; i += 256) {
        int p = i / 884; int rem = i % 884;
        int r = rem / 34, cl = rem % 34;
        int ci = p / 3, kt = p % 3;
        int lt = t + kt - 1;
        int yy = y0 + r - 1, xx = x0 + cl - 1;
        float v = 0.f;
        if (lt >= 0 && lt <= 15 && yy >= 0 && yy < 96 && xx >= 0 && xx < 96)
            v = x[((size_t)(n * 3 + ci) * 64 + (t0 + lt)) * 9216 + yy * 96 + cl + x0 - 1];
        tile[p * 936 + r * 36 + cl] = v;
    }
    __syncthreads();

    int cg = tid & 15;            // lane-fixed channel pair
    int co0 = cg * 2;
    float bv0 = bias[co0], bv1 = bias[co0 + 1];
    float ls0 = 0.f, lq0 = 0.f, ls1 = 0.f, lq1 = 0.f;
    size_t nt48 = (size_t)(n * 16 + t) * 48;

    #pragma unroll 1
    for (int rr = 0; rr < 3; ++rr) {
        int sp = rr * 16 + (tid >> 4);
        int tx = sp & 7, ty = sp >> 3;
        f32x4 a0_0 = (f32x4)bv0, a0_1 = (f32x4)bv0, a0_2 = (f32x4)bv0, a0_3 = (f32x4)bv0;
        f32x4 a1_0 = (f32x4)bv1, a1_1 = (f32x4)bv1, a1_2 = (f32x4)bv1, a1_3 = (f32x4)bv1;

        #pragma unroll 1
        for (int p = 0; p < 9; ++p) {
            const float* wpk = wl + ((p * 32 + co0) * 12);
            f32x4 wv0 = *(const f32x4*)(wpk);
            f32x4 wv1 = *(const f32x4*)(wpk + 4);
            f32x4 wv2 = *(const f32x4*)(wpk + 8);
            f32x4 wv3 = *(const f32x4*)(wpk + 12);
            f32x4 wv4 = *(const f32x4*)(wpk + 16);
            f32x4 wv5 = *(const f32x4*)(wpk + 20);
            float wa0 = wv0.x, wa1 = wv0.y, wa2 = wv0.z, wa3 = wv0.w;
            float wa4 = wv1.x, wa5 = wv1.y, wa6 = wv1.z, wa7 = wv1.w;
            float wa8 = wv2.x;
            float wb0 = wv3.x, wb1 = wv3.y, wb2 = wv3.z, wb3 = wv3.w;
            float wb4 = wv4.x, wb5 = wv4.y, wb6 = wv4.z, wb7 = wv4.w;
            float wb8 = wv5.x;
            const float* ip = tile + p * 936 + (ty * 4) * 36 + tx * 4;
            { C1LOADR(0) C1UPD0(0) }
            { C1LOADR(1) C1UPD0(1) C1UPD1(0) }
            { C1LOADR(2) C1UPD0(2) C1UPD1(1) C1UPD2(0) }
            { C1LOADR(3) C1UPD0(3) C1UPD1(2) C1UPD2(1) }
            { C1LOADR(4) C1UPD1(3) C1UPD2(2) }
            { C1LOADR(5) C1UPD2(3) }
        }

        // stats (full-res, pre-pool), accumulate in registers across rounds
        f32x4 s4 = a0_0 + a0_1 + a0_2 + a0_3;
        ls0 += s4.x + s4.y + s4.z + s4.w;
        f32x4 q4 = a0_0 * a0_0 + a0_1 * a0_1 + a0_2 * a0_2 + a0_3 * a0_3;
        lq0 += q4.x + q4.y + q4.z + q4.w;
        f32x4 s5 = a1_0 + a1_1 + a1_2 + a1_3;
        ls1 += s5.x + s5.y + s5.z + s5.w;
        f32x4 q5 = a1_0 * a1_0 + a1_1 * a1_1 + a1_2 * a1_2 + a1_3 * a1_3;
        lq1 += q5.x + q5.y + q5.z + q5.w;

        // 2x2 max/min pool in-register, direct coalesced stores
        f32x4 mx0a = vmax4(a0_0, a0_1), mx0b = vmax4(a0_2, a0_3);
        f32x4 mn0a = vmin4(a0_0, a0_1), mn0b = vmin4(a0_2, a0_3);
        f32x4 mx1a = vmax4(a1_0, a1_1), mx1b = vmax4(a1_2, a1_3);
        f32x4 mn1a = vmin4(a1_0, a1_1), mn1b = vmin4(a1_2, a1_3);
        size_t row0 = (nt48 + (size_t)(yt * 12 + ty * 2)) * 1536 + (size_t)(xt * 16 + tx * 2) * 32 + co0;
        size_t row1 = row0 + 1536;
        *(float2*)(pmax + row0)      = make_float2(fmaxf(mx0a.x, mx0a.y), fmaxf(mx1a.x, mx1a.y));
        *(float2*)(pmax + row0 + 32) = make_float2(fmaxf(mx0a.z, mx0a.w), fmaxf(mx1a.z, mx1a.w));
        *(float2*)(pmax + row1)      = make_float2(fmaxf(mx0b.x, mx0b.y), fmaxf(mx1b.x, mx1b.y));
        *(float2*)(pmax + row1 + 32) = make_float2(fmaxf(mx0b.z, mx0b.w), fmaxf(mx1b.z, mx1b.w));
        *(float2*)(pmin + row0)      = make_float2(fminf(mn0a.x, mn0a.y), fminf(mn1a.x, mn1a.y));
        *(float2*)(pmin + row0 + 32) = make_float2(fminf(mn0a.z, mn0a.w), fminf(mn1a.z, mn1a.w));
        *(float2*)(pmin + row1)      = make_float2(fminf(mn0b.x, mn0b.y), fminf(mn1b.x, mn1b.y));
        *(float2*)(pmin + row1 + 32) = make_float2(fminf(mn0b.z, mn0b.w), fminf(mn1b.z, mn1b.w));
    }

    // stats: reduce lanes sharing cg (stride 16/32 within wave), then LDS+global
    ls0 += __shfl_xor(ls0, 16, 64); ls0 += __shfl_xor(ls0, 32, 64);
    lq0 += __shfl_xor(lq0, 16, 64); lq0 += __shfl_xor(lq0, 32, 64);
    ls1 += __shfl_xor(ls1, 16, 64); ls1 += __shfl_xor(ls1, 32, 64);
    lq1 += __shfl_xor(lq1, 16, 64); lq1 += __shfl_xor(lq1, 32, 64);
    if ((tid & 63) < 16) {
        atomicAdd(&sst[co0 * 2], ls0);
        atomicAdd(&sst[co0 * 2 + 1], lq0);
        atomicAdd(&sst[co0 * 2 + 2], ls1);
        atomicAdd(&sst[co0 * 2 + 3], lq1);
    }
    __syncthreads();
    if (tid < 64) atomicAdd(&stats[tid], sst[tid]);
}

// -------- bnpool1b: pooled max/min -> BN affine + ReLU -> P2 hi/lo ----------
__global__ void bnpool1b(const float* __restrict__ pmax, const float* __restrict__ pmin,
                         const float* __restrict__ st, const float* __restrict__ gam,
                         const float* __restrict__ bet,
                         unsigned short* __restrict__ phi, unsigned short* __restrict__ plo) {
    int i = blockIdx.x * 256 + threadIdx.x;    // 589824 = 4*16*48*48*4
    int c8 = i & 3; int xo = (i >> 2) % 48; int yo = (i / 192) % 48;
    int t = (i / 9216) % 16; int n = i / 147456;
    size_t base = (((size_t)(n * 16 + t) * 48 + yo) * 48 + xo) * 32 + c8 * 8;
    union { unsigned short s[8]; uint4 v; } Uh, Ul;
    #pragma unroll
    for (int j = 0; j < 8; ++j) {
        int ch = c8 * 8 + j;
        float mean = st[ch * 2] * (1.f / 589824.f);
        float var  = st[ch * 2 + 1] * (1.f / 589824.f) - mean * mean;
        var = var < 0.f ? 0.f : var;
        float sc = gam[ch] / sqrtf(var + 1e-5f);
        float sh = bet[ch] - mean * sc;
        float pv = sc >= 0.f ? pmax[base + j] : pmin[base + j];
        float v = fmaxf(sc * pv + sh, 0.f);
        Uh.s[j] = f2bf(v);
        Ul.s[j] = f2bf(v - bf2f(Uh.s[j]));
    }
    size_t off = ((((size_t)n * 18 + t + 1) * 50 + yo + 1) * 52 + (xo + 1)) * 32 + c8 * 8;
    *(uint4*)(phi + off) = Uh.v;
    *(uint4*)(plo + off) = Ul.v;
}

// -------- conv2: 2-row x 32-co waves. Padded LDS [12][52][40] (stride 80B,
// conflict-free). Per step: 4 weight loads, 12 B ds_reads. -------------------
__launch_bounds__(256, 3)
__global__ void conv2k(const unsigned short* __restrict__ phi, const unsigned short* __restrict__ plo,
                       const unsigned short* __restrict__ w2p, const float* __restrict__ bias,
                       float* __restrict__ out, float* __restrict__ st) {
    __shared__ unsigned short tin[12 * 52 * 40];      // 24960 shorts = 49920 B
    float (*sred)[32] = (float (*)[32])(tin);          // alias: epilogue only
    float (*qred)[32] = (float (*)[32])(tin + 256);
    // XCD swizzle: 768 = 8 chunks x 96; chunk = (n, t-half).
    int b = blockIdx.x;
    int k8 = b & 7, i96 = b >> 3;
    int n = k8 >> 1, th = k8 & 1;
    int tt = i96 / 12; int y0 = (i96 - tt * 12) * 4;
    int t = th * 8 + tt;
    int w = threadIdx.x >> 6, lane = threadIdx.x & 63;
    int c = lane & 15, q = lane >> 4;
    int lrow = (w & 1) * 2, h2 = w >> 1;

    f32x4 acc[2][2][3];                                // [rr][mb'][xt]
    #pragma unroll
    for (int i = 0; i < 2; ++i)
        #pragma unroll
        for (int j = 0; j < 2; ++j)
            #pragma unroll
            for (int k = 0; k < 3; ++k) acc[i][j][k] = (f32x4)0.f;

    const int loff = h2 * 1024 + c * 32 + q * 8;       // weight lane offset (shorts)
    int tbo[2][3];                                     // B base offsets (shorts)
    #pragma unroll
    for (int rr = 0; rr < 2; ++rr)
        #pragma unroll
        for (int xt = 0; xt < 3; ++xt)
            tbo[rr][xt] = ((lrow + rr) * 52 + xt * 16 + c) * 40 + q * 8;

    #pragma unroll 1
    for (int kt = 0; kt < 3; ++kt) {
        const unsigned short* srch = phi + (size_t)(n * 18 + t + kt) * (50 * 52 * 32);
        const unsigned short* srcl = plo + (size_t)(n * 18 + t + kt) * (50 * 52 * 32);
        const unsigned short* wkt = w2p + kt * 36864;   // uniform (SGPR)
        __syncthreads();
        for (int i = threadIdx.x; i < 2496; i += 256) { // 12*52*4 16B-chunks
            int g = i & 3; int xx = (i >> 2) % 52; int rh = (i >> 2) / 52;
            int row = rh % 6; int h = rh / 6;
            const unsigned short* src = (h ? srcl : srch) + (size_t)(y0 + row) * 1664 + xx * 32 + g * 8;
            *(uint4*)(tin + (rh * 52 + xx) * 40 + (g << 3)) = *(const uint4*)src;
        }
        __syncthreads();
        #pragma unroll
        for (int ky = 0; ky < 3; ++ky) {
            #pragma unroll
            for (int kx = 0; kx < 3; ++kx) {
                const unsigned short* wb = wkt + (ky * 3 + kx) * 4096 + loff;
                short8 a0 = *(const short8*)(wb);
                short8 a1 = *(const short8*)(wb + 512);
                short8 l0 = *(const short8*)(wb + 2048);
                short8 l1 = *(const short8*)(wb + 2560);
                int off = (ky * 52 + kx) * 40;          // compile-time per step
                #pragma unroll
                for (int rr = 0; rr < 2; ++rr) {
                    short8 bh0 = *(const short8*)(tin + tbo[rr][0] + off);
                    short8 bl0 = *(const short8*)(tin + tbo[rr][0] + off + 12480);
                    short8 bh1 = *(const short8*)(tin + tbo[rr][1] + off);
                    short8 bl1 = *(const short8*)(tin + tbo[rr][1] + off + 12480);
                    short8 bh2 = *(const short8*)(tin + tbo[rr][2] + off);
                    short8 bl2 = *(const short8*)(tin + tbo[rr][2] + off + 12480);
                    MF(acc[rr][0][0], a0, bh0); MF(acc[rr][0][0], a0, bl0); MF(acc[rr][0][0], l0, bh0);
                    MF(acc[rr][0][1], a0, bh1); MF(acc[rr][0][1], a0, bl1); MF(acc[rr][0][1], l0, bh1);
                    MF(acc[rr][0][2], a0, bh2); MF(acc[rr][0][2], a0, bl2); MF(acc[rr][0][2], l0, bh2);
                    MF(acc[rr][1][0], a1, bh0); MF(acc[rr][1][0], a1, bl0); MF(acc[rr][1][0], l1, bh0);
                    MF(acc[rr][1][1], a1, bh1); MF(acc[rr][1][1], a1, bl1); MF(acc[rr][1][1], l1, bh1);
                    MF(acc[rr][1][2], a1, bh2); MF(acc[rr][1][2], a1, bl2); MF(acc[rr][1][2], l1, bh2);
                }
            }
        }
    }
    __syncthreads();        // fence: tin reads done before sred/qred alias writes
    #pragma unroll
    for (int mbp = 0; mbp < 2; ++mbp) {
        f32x4 bv = *(const f32x4*)(bias + h2 * 32 + mbp * 16 + q * 4);
        float s0 = 0.f, s1 = 0.f, s2 = 0.f, s3 = 0.f;
        float p0 = 0.f, p1 = 0.f, p2 = 0.f, p3 = 0.f;
        #pragma unroll
        for (int rr = 0; rr < 2; ++rr) {
            int y = y0 + lrow + rr;
            float* ob = out + (((size_t)(n * 16 + t) * 48) + y) * (48 * 64) + h2 * 32 + mbp * 16 + q * 4;
            #pragma unroll
            for (int xt = 0; xt < 3; ++xt) {
                f32x4 v = acc[rr][mbp][xt] + bv;
                *(f32x4*)(ob + (xt * 16 + c) * 64) = v;
                s0 += v.x; s1 += v.y; s2 += v.z; s3 += v.w;
                p0 += v.x * v.x; p1 += v.y * v.y; p2 += v.z * v.z; p3 += v.w * v.w;
            }
        }
        float sv[4] = {s0, s1, s2, s3}, qv[4] = {p0, p1, p2, p3};
        #pragma unroll
        for (int r = 0; r < 4; ++r) {
            float s = sv[r], q2 = qv[r];
            #pragma unroll
            for (int m = 1; m < 16; m <<= 1) { s += __shfl_xor(s, m, 64); q2 += __shfl_xor(q2, m, 64); }
            if (c == 0) { sred[w][mbp * 16 + q * 4 + r] = s; qred[w][mbp * 16 + q * 4 + r] = q2; }
        }
    }
    __syncthreads();
    if (threadIdx.x < 64) {
        int h = threadIdx.x >> 5, loc = threadIdx.x & 31;
        float s = sred[2 * h][loc] + sred[2 * h + 1][loc];
        float q2 = qred[2 * h][loc] + qred[2 * h + 1][loc];
        atomicAdd(&st[threadIdx.x * 2], s);
        atomicAdd(&st[threadIdx.x * 2 + 1], q2);
    }
}

// -------- bnpool2: conv2 out chan-last -> P3 [n][18][26][34][64] hi/lo ------
__global__ void bnpool2k(const float* __restrict__ cin, const float* __restrict__ st,
                         const float* __restrict__ gam, const float* __restrict__ bet,
                         unsigned short* __restrict__ phi, unsigned short* __restrict__ plo) {
    int i = blockIdx.x * 256 + threadIdx.x;    // 509184
    if (i >= 509184) return;
    int oc = i & 7; int xp = (i >> 3) % 34; int yp = (i / 272) % 26;
    int tp = (i / 7072) % 18; int n = i / 127296;
    union { unsigned short s[8]; uint4 v; } Uh, Ul;
    if (tp >= 1 && tp <= 16 && yp >= 1 && yp <= 24 && xp >= 1 && xp <= 24) {
        int t = tp - 1, yo = yp - 1, xo = xp - 1;
        const float* b0 = cin + ((((size_t)(n * 16 + t) * 48) + 2 * yo) * 48 + 2 * xo) * 64 + oc * 8;
        #pragma unroll
        for (int j = 0; j < 8; ++j) {
            int ch = oc * 8 + j;
            float mean = st[ch * 2] * (1.f / 147456.f);
            float var  = st[ch * 2 + 1] * (1.f / 147456.f) - mean * mean;
            var = var < 0.f ? 0.f : var;
            float sc = gam[ch] / sqrtf(var + 1e-5f);
            float sh = bet[ch] - mean * sc;
            float a  = b0[j] * sc + sh;
            float bb = b0[64 + j] * sc + sh;
            float c2 = b0[3072 + j] * sc + sh;
            float d  = b0[3136 + j] * sc + sh;
            float v = fmaxf(fmaxf(fmaxf(a, bb), fmaxf(c2, d)), 0.f);
            Uh.s[j] = f2bf(v);
            Ul.s[j] = f2bf(v - bf2f(Uh.s[j]));
        }
    } else {
        Uh.v = make_uint4(0, 0, 0, 0);
        Ul.v = make_uint4(0, 0, 0, 0);
    }
    size_t off = ((((size_t)n * 18 + tp) * 26 + yp) * 34 + xp) * 64 + oc * 8;
    *(uint4*)(phi + off) = Uh.v;
    *(uint4*)(plo + off) = Ul.v;
}

// -------- conv3: 2-row x 32-co waves. r13 XOR LDS layout (39936B). Per step:
// 4 weight loads, 8 B ds_reads. ---------------------------------------------
__launch_bounds__(256, 3)
__global__ void conv3k(const unsigned short* __restrict__ phi, const unsigned short* __restrict__ plo,
                       const unsigned short* __restrict__ w3p, const float* __restrict__ bias,
                       float* __restrict__ out, float* __restrict__ st) {
    __shared__ unsigned short tin[12 * 26 * 64];      // 19968 shorts = 39936 B
    float (*sred)[32] = (float (*)[32])(tin);          // alias: epilogue only
    float (*qred)[32] = (float (*)[32])(tin + 256);
    // XCD swizzle: 768 = 8 chunks x 96; chunk = (n, t-half), both cg inside.
    int b = blockIdx.x;
    int k8 = b & 7, i96 = b >> 3;
    int n = k8 >> 1, th = k8 & 1;
    int cg = i96 / 48; int r48 = i96 - cg * 48;
    int tt = r48 / 6;  int y0 = (r48 - tt * 6) * 4;
    int t = th * 8 + tt;
    int w = threadIdx.x >> 6, lane = threadIdx.x & 63;
    int c = lane & 15, q = lane >> 4;
    int lrow = (w & 1) * 2, h2 = w >> 1;

    f32x4 acc[2][2][2];                                // [rr][mb'][xt]
    #pragma unroll
    for (int i = 0; i < 2; ++i)
        #pragma unroll
        for (int j = 0; j < 2; ++j) { acc[i][j][0] = (f32x4)0.f; acc[i][j][1] = (f32x4)0.f; }

    const unsigned short* wsrc = w3p + (size_t)cg * 221184 + h2 * 1024 + c * 32 + q * 8;

    #pragma unroll 1
    for (int kt = 0; kt < 3; ++kt) {
        const unsigned short* srch = phi + (size_t)(n * 18 + t + kt) * (26 * 34 * 64);
        const unsigned short* srcl = plo + (size_t)(n * 18 + t + kt) * (26 * 34 * 64);
        const unsigned short* wkt = wsrc + kt * 73728;
        __syncthreads();
        for (int i = threadIdx.x; i < 2496; i += 256) {     // 12*26*8 16B-chunks
            int g = i & 7; int xx = (i >> 3) % 26; int rh = (i >> 3) / 26;
            int row = rh % 6; int h = rh / 6;
            const unsigned short* src = (h ? srcl : srch) + (size_t)(y0 + row) * 2176 + xx * 64 + g * 8;
            *(uint4*)(tin + ((rh * 26 + xx) << 6) + ((g ^ (xx & 7)) << 3)) = *(const uint4*)src;
        }
        __syncthreads();
        #pragma unroll
        for (int ky = 0; ky < 3; ++ky) {
            #pragma unroll
            for (int kx = 0; kx < 3; ++kx) {
                #pragma unroll
                for (int kc = 0; kc < 2; ++kc) {
                    const unsigned short* wb = wkt + ky * 24576 + kx * 8192 + kc * 2048;
                    short8 a0 = *(const short8*)(wb);
                    short8 a1 = *(const short8*)(wb + 512);
                    short8 l0 = *(const short8*)(wb + 4096);
                    short8 l1 = *(const short8*)(wb + 4608);
                    int x0 = kx + c;
                    int x1t = 16 + kx + c;
                    int x1 = x1t > 25 ? 25 : x1t;   // c>=8 @ xt=1: discarded cols, finite junk
                    int so0 = ((kc * 4 + q) ^ (x0 & 7)) << 3;
                    int so1 = ((kc * 4 + q) ^ (x1 & 7)) << 3;
                    #pragma unroll
                    for (int rr = 0; rr < 2; ++rr) {
                        int row = lrow + rr + ky;
                        short8 bh0 = *(const short8*)(tin + ((row * 26 + x0) << 6) + so0);
                        short8 bl0 = *(const short8*)(tin + (((6 + row) * 26 + x0) << 6) + so0);
                        short8 bh1 = *(const short8*)(tin + ((row * 26 + x1) << 6) + so1);
                        short8 bl1 = *(const short8*)(tin + (((6 + row) * 26 + x1) << 6) + so1);
                        MF(acc[rr][0][0], a0, bh0); MF(acc[rr][0][0], a0, bl0); MF(acc[rr][0][0], l0, bh0);
                        MF(acc[rr][0][1], a0, bh1); MF(acc[rr][0][1], a0, bl1); MF(acc[rr][0][1], l0, bh1);
                        MF(acc[rr][1][0], a1, bh0); MF(acc[rr][1][0], a1, bl0); MF(acc[rr][1][0], l1, bh0);
                        MF(acc[rr][1][1], a1, bh1); MF(acc[rr][1][1], a1, bl1); MF(acc[rr][1][1], l1, bh1);
                    }
                }
            }
        }
    }
    __syncthreads();        // fence: tin reads done before sred/qred alias writes
    #pragma unroll
    for (int mbp = 0; mbp < 2; ++mbp) {
        f32x4 bv = *(const f32x4*)(bias + cg * 64 + h2 * 32 + mbp * 16 + q * 4);
        float s0 = 0.f, s1 = 0.f, s2 = 0.f, s3 = 0.f;
        float p0 = 0.f, p1 = 0.f, p2 = 0.f, p3 = 0.f;
        #pragma unroll
        for (int rr = 0; rr < 2; ++rr) {
            int y = y0 + lrow + rr;
            float* ob = out + (((size_t)(n * 16 + t) * 24) + y) * (24 * 128) + cg * 64 + h2 * 32 + mbp * 16 + q * 4;
            f32x4 v0 = acc[rr][mbp][0] + bv;
            f32x4 v1 = acc[rr][mbp][1] + bv;
            *(f32x4*)(ob + c * 128) = v0;
            if (c < 8) *(f32x4*)(ob + (16 + c) * 128) = v1;
            float m = c < 8 ? 1.f : 0.f;
            s0 += v0.x + m * v1.x; s1 += v0.y + m * v1.y; s2 += v0.z + m * v1.z; s3 += v0.w + m * v1.w;
            p0 += v0.x * v0.x + m * v1.x * v1.x; p1 += v0.y * v0.y + m * v1.y * v1.y;
            p2 += v0.z * v0.z + m * v1.z * v1.z; p3 += v0.w * v0.w + m * v1.w * v1.w;
        }
        float sv[4] = {s0, s1, s2, s3}, qv[4] = {p0, p1, p2, p3};
        #pragma unroll
        for (int r = 0; r < 4; ++r) {
            float s = sv[r], q2 = qv[r];
            #pragma unroll
            for (int m = 1; m < 16; m <<= 1) { s += __shfl_xor(s, m, 64); q2 += __shfl_xor(q2, m, 64); }
            if (c == 0) { sred[w][mbp * 16 + q * 4 + r] = s; qred[w][mbp * 16 + q * 4 + r] = q2; }
        }
    }
    __syncthreads();
    if (threadIdx.x < 64) {
        int h = threadIdx.x >> 5, loc = threadIdx.x & 31;
        int co = cg * 64 + threadIdx.x;
        float s = sred[2 * h][loc] + sred[2 * h + 1][loc];
        float q2 = qred[2 * h][loc] + qred[2 * h + 1][loc];
        atomicAdd(&st[co * 2], s);
        atomicAdd(&st[co * 2 + 1], q2);
    }
}

// -------- BN + ReLU + avgpool 6x6 (chan-last in) -> enc ---------------------
__global__ void bnavgk(const float* __restrict__ x, const float* __restrict__ st,
                       const float* __restrict__ gam, const float* __restrict__ bet,
                       float* __restrict__ enc) {
    int i = blockIdx.x * 256 + threadIdx.x;    // 131072
    int c = i & 127; int xo = (i >> 7) & 3; int yo = (i >> 9) & 3;
    int t = (i >> 11) & 15; int n = i >> 15;
    float mean = st[c * 2] * (1.f / 36864.f);
    float var  = st[c * 2 + 1] * (1.f / 36864.f) - mean * mean;
    var = var < 0.f ? 0.f : var;
    float sc = gam[c] / sqrtf(var + 1e-5f);
    float sh = bet[c] - mean * sc;
    const float* base = x + ((((size_t)(n * 16 + t) * 24) + yo * 6) * 24 + xo * 6) * 128 + c;
    float s = 0.f;
    #pragma unroll
    for (int wy = 0; wy < 6; ++wy)
        #pragma unroll
        for (int wx = 0; wx < 6; ++wx)
            s += fmaxf(base[(wy * 24 + wx) * 128] * sc + sh, 0.f);
    enc[(size_t)n * 32768 + (size_t)c * 256 + t * 16 + yo * 4 + xo] = s * (1.f / 36.f);
}

// -------- weight prepack kernels -------------------------------------------
__global__ void prep2k(const float* __restrict__ c2w, unsigned short* __restrict__ w2p) {
    int i = blockIdx.x * 256 + threadIdx.x;    // 110592
    if (i >= 110592) return;
    int ci = i & 31; int co = (i >> 5) & 63; int h = (i >> 11) & 1;
    int o = (i >> 12) % 9; int kt = i / 36864;
    int ky = o / 3, kx = o % 3;
    float w = c2w[(((size_t)(co * 32 + ci) * 3 + kt) * 3 + ky) * 3 + kx];
    unsigned short hi = f2bf(w);
    w2p[i] = h ? f2bf(w - bf2f(hi)) : hi;
}
__global__ void prep3k(const float* __restrict__ c3w, unsigned short* __restrict__ w3p) {
    int i = blockIdx.x * 256 + threadIdx.x;    // 442368
    if (i >= 442368) return;
    int cil = i & 31; int cop = (i >> 5) & 63; int kc = (i >> 11) & 1; int h = (i >> 12) & 1;
    int kx = (i >> 13) % 3; int ky = (i / 24576) % 3; int kt = (i / 73728) % 3; int cg = i / 221184;
    int ci = kc * 32 + cil; int co = cg * 64 + cop;
    float w = c3w[(((size_t)(co * 64 + ci) * 3 + kt) * 3 + ky) * 3 + kx];
    unsigned short hi = f2bf(w);
    w3p[i] = h ? f2bf(w - bf2f(hi)) : hi;
}
__global__ void prepwhhk(const float* __restrict__ whh, float* __restrict__ wt) {
    int i = blockIdx.x * 256 + threadIdx.x;    // 196608
    int g = i % 768, k = i / 768;
    wt[i] = whh[(size_t)g * 256 + k];
}

// -------- codebook transpose: cb[8192][256] -> cbT[256][8192] ---------------
__global__ void transck(const float* __restrict__ cb, float* __restrict__ cbT) {
    __shared__ float t[32][33];
    int bx = blockIdx.x & 255;
    int by = blockIdx.x >> 8;
    int ld = threadIdx.x & 31, lk = threadIdx.x >> 5;
    #pragma unroll
    for (int i = 0; i < 4; ++i) {
        int kl = lk + i * 8;
        t[kl][ld] = cb[(size_t)(bx * 32 + kl) * 256 + by * 32 + ld];
    }
    __syncthreads();
    #pragma unroll
    for (int i = 0; i < 4; ++i) {
        int dl = lk + i * 8;
        cbT[(size_t)(by * 32 + dl) * 8192 + bx * 32 + ld] = t[ld][dl];
    }
}

// -------- code norms in fp64 (ascending d, matches reference order) ---------
__global__ void cnormk(const float* __restrict__ cbT, double* __restrict__ cn2) {
    int k = blockIdx.x * 256 + threadIdx.x;    // 8192
    double s = 0.0;
    for (int d = 0; d < 256; ++d) {
        double c = (double)cbT[(size_t)d * 8192 + k];
        s += c * c;
    }
    cn2[k] = s;
}

// -------- proj init: feat = pb broadcast ------------------------------------
__global__ void projinitk(const float* __restrict__ pb, float* __restrict__ feat) {
    int i = blockIdx.x * 256 + threadIdx.x;    // 7168
    feat[i] = pb[i & 255];
}

// -------- proj (K-split x8): feat[r][d] += enc[r-chunk] . pw[d-chunk] -------
__global__ void projk(const float* __restrict__ enc, const float* __restrict__ pw,
                      float* __restrict__ feat) {
    int d = blockIdx.x & 255; int ch = blockIdx.x >> 8;    // 2048 blocks
    int k0 = ch * 4096;
    float acc[28];
    #pragma unroll
    for (int e = 0; e < 28; ++e) acc[e] = 0.f;
    const float* wrow = pw + (size_t)d * 32768 + k0;
    for (int k = threadIdx.x; k < 4096; k += 256) {
        float wv = wrow[k];
        #pragma unroll
        for (int e = 0; e < 28; ++e) acc[e] += enc[(size_t)e * 32768 + k0 + k] * wv;
    }
    __shared__ float red[4 * 28];
    #pragma unroll
    for (int e = 0; e < 28; ++e) {
        float v = acc[e];
        #pragma unroll
        for (int o = 32; o > 0; o >>= 1) v += __shfl_down(v, o, 64);
        if ((threadIdx.x & 63) == 0) red[(threadIdx.x >> 6) * 28 + e] = v;
    }
    __syncthreads();
    if (threadIdx.x < 28) {
        int e = threadIdx.x;
        int l = e >> 2, n = e & 3;
        float s = red[e] + red[28 + e] + red[56 + e] + red[84 + e];
        atomicAdd(&feat[(size_t)(n * 7 + l) * 256 + d], s);
    }
}

// -------- VQ: argmin over transposed codebook, fp64, 896 blocks -------------
__global__ void quantk(const float* __restrict__ feat, const float* __restrict__ cbT,
                       const double* __restrict__ cn2, unsigned long long* __restrict__ best) {
    int kc = blockIdx.x & 31, r = blockIdx.x >> 5;     // 896 = 32kc * 28r
    int k = kc * 256 + threadIdx.x;
    __shared__ float fs[256];
    fs[threadIdx.x] = feat[(size_t)r * 256 + threadIdx.x];
    __syncthreads();
    double dot = 0.0;
    for (int d = 0; d < 256; ++d)
        dot += (double)cbT[(size_t)d * 8192 + k] * (double)fs[d];
    float s = (float)(cn2[k] - 2.0 * dot);
    unsigned int bits = __float_as_uint(s);
    unsigned int key = (bits & 0x80000000u) ? ~bits : (bits | 0x80000000u);
    unsigned long long p = ((unsigned long long)key << 32) | (unsigned int)k;
    #pragma unroll
    for (int o = 32; o > 0; o >>= 1) {
        unsigned long long qv = __shfl_down(p, o, 64);
        if (qv < p) p = qv;
    }
    if ((threadIdx.x & 63) == 0) atomicMin(&best[r], p);
}

__global__ void gatherk(const unsigned long long* __restrict__ best,
                        const float* __restrict__ feat, const float* __restrict__ cb,
                        float* __restrict__ dout, float* __restrict__ quant,
                        float* __restrict__ acc) {
    int r = blockIdx.x;
    int d = threadIdx.x;
    int idx = (int)(best[r] & 0xFFFFFFFFull);
    float q = cb[(size_t)idx * 256 + d];
    quant[r * 256 + d] = q;
    dout[28 + r * 256 + d] = q;
    if (d == 0) dout[r] = (float)idx;
    float df = feat[r * 256 + d] - q;
    float v = df * df;
    #pragma unroll
    for (int o = 32; o > 0; o >>= 1) v += __shfl_down(v, o, 64);
    if ((d & 63) == 0) atomicAdd(&acc[0], v);
}

__global__ void gxk(const float* __restrict__ quant, const float* __restrict__ wih,
                    const float* __restrict__ bih, float* __restrict__ gx) {
    int o = blockIdx.x * 256 + threadIdx.x;
    int g = o % 768; int t = (o / 768) % 6; int n = o / (768 * 6);
    const float* q = quant + (size_t)(n * 7 + t) * 256;
    const float* w = wih + (size_t)g * 256;
    float s = bih[g];
    #pragma unroll 4
    for (int d = 0; d < 256; ++d) s += q[d] * w[d];
    gx[o] = s;
}

// -------- all 6 GRU steps in one kernel (block = batch b) -------------------
__global__ void gru_allk(const float* __restrict__ gx, const float* __restrict__ wt,
                         const float* __restrict__ bhh, const float* __restrict__ feat,
                         float* __restrict__ acc) {
    int b = blockIdx.x;        // 4
    int d = threadIdx.x;       // 256
    __shared__ float hs[256];
    hs[d] = 0.f;
    __syncthreads();
    float ctx = 0.f;
    for (int t = 0; t < 6; ++t) {
        float g0 = bhh[d], g1 = bhh[256 + d], g2 = bhh[512 + d];
        #pragma unroll 4
        for (int k = 0; k < 256; ++k) {
            float hv = hs[k];
            const float* wr = wt + (size_t)k * 768;
            g0 += wr[d] * hv; g1 += wr[256 + d] * hv; g2 += wr[512 + d] * hv;
        }
        const float* gxr = gx + (size_t)(b * 6 + t) * 768;
        float xr = gxr[d], xz = gxr[256 + d], xn = gxr[512 + d];
        float rr = 1.f / (1.f + expf(-(xr + g0)));
        float zz = 1.f / (1.f + expf(-(xz + g1)));
        float nn = tanhf(xn + rr * g2);
        float h2 = (1.f - zz) * nn + zz * hs[d];
        __syncthreads();
        hs[d] = h2;
        __syncthreads();
        float df = h2 - feat[(size_t)(b * 7 + t + 1) * 256 + d];
        ctx += df * df;
    }
    #pragma unroll
    for (int o = 32; o > 0; o >>= 1) ctx += __shfl_down(ctx, o, 64);
    if ((d & 63) == 0) atomicAdd(&acc[1], ctx);
}

__global__ void fink(const float* __restrict__ acc, float* __restrict__ dout) {
    float comm = acc[0] / 7168.f;
    float ctx  = acc[1] / 6144.f;
    dout[7196] = comm;
    dout[7197] = comm;
    dout[7198] = ctx;
    dout[7199] = comm + 0.25f * comm + 0.1f * ctx;
}

// ---------------------------------------------------------------------------
extern "C" void kernel_launch(void* const* d_in, const int* in_sizes, int n_in,
                              void* d_out, int out_size, void* d_ws, size_t ws_size,
                              hipStream_t stream) {
    (void)in_sizes; (void)n_in; (void)out_size; (void)ws_size;
    const float* x    = (const float*)d_in[0];
    const float* c1w  = (const float*)d_in[1];
    const float* c1b  = (const float*)d_in[2];
    const float* bn1g = (const float*)d_in[3];
    const float* bn1b = (const float*)d_in[4];
    const float* c2w  = (const float*)d_in[5];
    const float* c2b  = (const float*)d_in[6];
    const float* bn2g = (const float*)d_in[7];
    const float* bn2b = (const float*)d_in[8];
    const float* c3w  = (const float*)d_in[9];
    const float* c3b  = (const float*)d_in[10];
    const float* bn3g = (const float*)d_in[11];
    const float* bn3b = (const float*)d_in[12];
    const float* pw   = (const float*)d_in[13];
    const float* pb   = (const float*)d_in[14];
    const float* cb   = (const float*)d_in[15];
    const float* wih  = (const float*)d_in[16];
    const float* whh  = (const float*)d_in[17];
    const float* bih  = (const float*)d_in[18];
    const float* bhh  = (const float*)d_in[19];
    float* out = (float*)d_out;

    // ---- workspace layout (bytes) ----
    char* w = (char*)d_ws;
    float* A  = (float*)w;                         w += 75497472;   // conv2/3 outs; pmax/pmin + cbT alias
    float* PMAX = A;                                                // 18.87 MB (alias)
    float* PMIN = A + 4718592;                                      // 18.87 MB (alias)
    float* cbT = A;                                                 // 8 MB (alias, post-loop)
    double* cn2 = (double*)((char*)A + 8388608);                    // 64 KB (alias, post-loop)
    char*  SH = w;                                 w += 16293888;   // P3 hi/lo
    unsigned short* P3h = (unsigned short*)SH;
    unsigned short* P3l = (unsigned short*)(SH + 8146944);
    unsigned short* P2h = (unsigned short*)w;      w += 11980800;
    unsigned short* P2l = (unsigned short*)w;      w += 11980800;
    unsigned short* W2P = (unsigned short*)w;      w += 221184;
    unsigned short* W3P = (unsigned short*)w;      w += 884736;
    float* WT    = (float*)w;                      w += 786432;     // whh transposed [256][768]
    float* enc   = (float*)w;                      w += 3670016;
    float* feat  = (float*)w;                      w += 28672;
    float* quant = (float*)w;                      w += 28672;
    float* gx    = (float*)w;                      w += 73728;
    float* statsA = (float*)w;                     w += 21504;      // 21 x 256 floats
    float* acc    = (float*)w;                     w += 16;
    unsigned long long* best = (unsigned long long*)w;  w += 224;

    // ---- per-launch init ----
    hipMemsetAsync(P2h, 0, 11980800 * 2, stream);                  // P2 hi+lo pads
    hipMemsetAsync(statsA, 0, 21504 + 16, stream);                 // stats + acc
    hipMemsetAsync(best, 0xFF, 224, stream);
    prep2k<<<432, 256, 0, stream>>>(c2w, W2P);
    prep3k<<<1728, 256, 0, stream>>>(c3w, W3P);
    prepwhhk<<<768, 256, 0, stream>>>(whh, WT);

    for (int l = 0; l < 7; ++l) {
        float* st1 = statsA + (l * 3 + 0) * 256;
        float* st2 = statsA + (l * 3 + 1) * 256;
        float* st3 = statsA + (l * 3 + 2) * 256;
        conv1k<<<768, 256, 0, stream>>>(x, c1w, c1b, PMAX, PMIN, st1, l * 8);
        bnpool1b<<<2304, 256, 0, stream>>>(PMAX, PMIN, st1, bn1g, bn1b, P2h, P2l);
        conv2k<<<768, 256, 0, stream>>>(P2h, P2l, W2P, c2b, A, st2);
        bnpool2k<<<1989, 256, 0, stream>>>(A, st2, bn2g, bn2b, P3h, P3l);
        conv3k<<<768, 256, 0, stream>>>(P3h, P3l, W3P, c3b, A, st3);
        bnavgk<<<512, 256, 0, stream>>>(A, st3, bn3g, bn3b, enc + (size_t)l * 131072);
    }

    // A is free now: build transposed codebook + norms in its space
    transck<<<2048, 256, 0, stream>>>(cb, cbT);
    cnormk<<<32, 256, 0, stream>>>(cbT, cn2);
    projinitk<<<28, 256, 0, stream>>>(pb, feat);
    projk<<<2048, 256, 0, stream>>>(enc, pw, feat);
    quantk<<<896, 256, 0, stream>>>(feat, cbT, cn2, best);
    gatherk<<<28, 256, 0, stream>>>(best, feat, cb, out, quant, acc);
    gxk<<<72, 256, 0, stream>>>(quant, wih, bih, gx);
    gru_allk<<<4, 256, 0, stream>>>(gx, WT, bhh, feat, acc);
    fink<<<1, 1, 0, stream>>>(acc, out);
}

// Round 9
// 2208.671 us; speedup vs baseline: 1.0829x; 1.0548x over previous
//
#include <hip/hip_runtime.h>
#include <math.h>

// ---------------------------------------------------------------------------
// VQSign r17: revert conv3k's r15 remap (it SPILLS: r16 profile shows FETCH
// 114MB / WRITE 85MB vs 10/19 expected, VGPR 84, dur 126us vs r13's 110.4).
// conv3k goes back to the r13 body verbatim (1-row x 64-co waves, 26-wide
// clamped XOR tile, simple loads: proven 110.4us / VGPR 52 / no spill).
// conv2k keeps the r15 2-row x 32-co remap (its 12-dsread/4-weight balance
// suits it; e2e accounting credits it ~-17us/iter). projk stays r14
// (2048 blocks, proven). Single-variable change vs r16.
// ---------------------------------------------------------------------------

typedef __attribute__((ext_vector_type(8))) short short8;
typedef __attribute__((ext_vector_type(4))) float f32x4;

__device__ inline unsigned short f2bf(float x) {
    unsigned int u = __float_as_uint(x);
    u += 0x7FFFu + ((u >> 16) & 1u);          // RNE
    return (unsigned short)(u >> 16);
}
__device__ inline float bf2f(unsigned short h) {
    return __uint_as_float(((unsigned int)h) << 16);
}
__device__ inline f32x4 vmax4(f32x4 a, f32x4 b) {
    return (f32x4){fmaxf(a.x, b.x), fmaxf(a.y, b.y), fmaxf(a.z, b.z), fmaxf(a.w, b.w)};
}
__device__ inline f32x4 vmin4(f32x4 a, f32x4 b) {
    return (f32x4){fminf(a.x, b.x), fminf(a.y, b.y), fminf(a.z, b.z), fminf(a.w, b.w)};
}

#define MF(d, a, b) d = __builtin_amdgcn_mfma_f32_16x16x32_bf16(a, b, d, 0, 0, 0)

// ---------------- conv1: fp32, LDS tile, pooled max/min chan-last out -------
#define C1LOADR(J) \
    f32x4 u = *(const f32x4*)(ip + (J) * 36); \
    f32x4 w4 = *(const f32x4*)(ip + (J) * 36 + 4); \
    f32x4 sA = u; \
    f32x4 sB = __builtin_shufflevector(u, w4, 1, 2, 3, 4); \
    f32x4 sC = __builtin_shufflevector(u, w4, 2, 3, 4, 5);
#define C1UPD0(I) a0_##I += wa0 * sA + wa1 * sB + wa2 * sC; a1_##I += wb0 * sA + wb1 * sB + wb2 * sC;
#define C1UPD1(I) a0_##I += wa3 * sA + wa4 * sB + wa5 * sC; a1_##I += wb3 * sA + wb4 * sB + wb5 * sC;
#define C1UPD2(I) a0_##I += wa6 * sA + wa7 * sB + wa8 * sC; a1_##I += wb6 * sA + wb7 * sB + wb8 * sC;

__launch_bounds__(256, 3)
__global__ void conv1k(const float* __restrict__ x, const float* __restrict__ wgt,
                       const float* __restrict__ bias, float* __restrict__ pmax,
                       float* __restrict__ pmin, float* __restrict__ stats, int t0) {
    int bb = blockIdx.x;
    int xt = bb % 3; int yt = (bb / 3) % 4; int t = (bb / 12) % 16; int n = bb / 192;
    int x0 = xt * 32, y0 = yt * 24;
    __shared__ float tile[9 * 936];           // [p=ci*3+kt][26 rows][36 (34 used)]
    __shared__ float wl[3456];                // [9p][32co][12 (9 used)] - b128 aligned
    __shared__ float sst[64];
    int tid = threadIdx.x;
    for (int i = tid; i < 3456; i += 256) {
        int idx = i % 12; int r = i / 12;
        int co = r & 31; int p = r >> 5;
        wl[i] = idx < 9 ? wgt[co * 81 + p * 9 + idx] : 0.f;
    }
    if (tid < 64) sst[tid] = 0.f;
    for (int i = tid; i < 7956; i += 256) {
        int p = i / 884; int rem = i % 884;
        int r = rem / 34, cl = rem % 34;
        int ci = p / 3, kt = p % 3;
        int lt = t + kt - 1;
        int yy = y0 + r - 1, xx = x0 + cl - 1;
        float v = 0.f;
        if (lt >= 0 && lt <= 15 && yy >= 0 && yy < 96 && xx >= 0 && xx < 96)
            v = x[((size_t)(n * 3 + ci) * 64 + (t0 + lt)) * 9216 + yy * 96 + cl + x0 - 1];
        tile[p * 936 + r * 36 + cl] = v;
    }
    __syncthreads();

    int cg = tid & 15;            // lane-fixed channel pair
    int co0 = cg * 2;
    float bv0 = bias[co0], bv1 = bias[co0 + 1];
    float ls0 = 0.f, lq0 = 0.f, ls1 = 0.f, lq1 = 0.f;
    size_t nt48 = (size_t)(n * 16 + t) * 48;

    #pragma unroll 1
    for (int rr = 0; rr < 3; ++rr) {
        int sp = rr * 16 + (tid >> 4);
        int tx = sp & 7, ty = sp >> 3;
        f32x4 a0_0 = (f32x4)bv0, a0_1 = (f32x4)bv0, a0_2 = (f32x4)bv0, a0_3 = (f32x4)bv0;
        f32x4 a1_0 = (f32x4)bv1, a1_1 = (f32x4)bv1, a1_2 = (f32x4)bv1, a1_3 = (f32x4)bv1;

        #pragma unroll 1
        for (int p = 0; p < 9; ++p) {
            const float* wpk = wl + ((p * 32 + co0) * 12);
            f32x4 wv0 = *(const f32x4*)(wpk);
            f32x4 wv1 = *(const f32x4*)(wpk + 4);
            f32x4 wv2 = *(const f32x4*)(wpk + 8);
            f32x4 wv3 = *(const f32x4*)(wpk + 12);
            f32x4 wv4 = *(const f32x4*)(wpk + 16);
            f32x4 wv5 = *(const f32x4*)(wpk + 20);
            float wa0 = wv0.x, wa1 = wv0.y, wa2 = wv0.z, wa3 = wv0.w;
            float wa4 = wv1.x, wa5 = wv1.y, wa6 = wv1.z, wa7 = wv1.w;
            float wa8 = wv2.x;
            float wb0 = wv3.x, wb1 = wv3.y, wb2 = wv3.z, wb3 = wv3.w;
            float wb4 = wv4.x, wb5 = wv4.y, wb6 = wv4.z, wb7 = wv4.w;
            float wb8 = wv5.x;
            const float* ip = tile + p * 936 + (ty * 4) * 36 + tx * 4;
            { C1LOADR(0) C1UPD0(0) }
            { C1LOADR(1) C1UPD0(1) C1UPD1(0) }
            { C1LOADR(2) C1UPD0(2) C1UPD1(1) C1UPD2(0) }
            { C1LOADR(3) C1UPD0(3) C1UPD1(2) C1UPD2(1) }
            { C1LOADR(4) C1UPD1(3) C1UPD2(2) }
            { C1LOADR(5) C1UPD2(3) }
        }

        // stats (full-res, pre-pool), accumulate in registers across rounds
        f32x4 s4 = a0_0 + a0_1 + a0_2 + a0_3;
        ls0 += s4.x + s4.y + s4.z + s4.w;
        f32x4 q4 = a0_0 * a0_0 + a0_1 * a0_1 + a0_2 * a0_2 + a0_3 * a0_3;
        lq0 += q4.x + q4.y + q4.z + q4.w;
        f32x4 s5 = a1_0 + a1_1 + a1_2 + a1_3;
        ls1 += s5.x + s5.y + s5.z + s5.w;
        f32x4 q5 = a1_0 * a1_0 + a1_1 * a1_1 + a1_2 * a1_2 + a1_3 * a1_3;
        lq1 += q5.x + q5.y + q5.z + q5.w;

        // 2x2 max/min pool in-register, direct coalesced stores
        f32x4 mx0a = vmax4(a0_0, a0_1), mx0b = vmax4(a0_2, a0_3);
        f32x4 mn0a = vmin4(a0_0, a0_1), mn0b = vmin4(a0_2, a0_3);
        f32x4 mx1a = vmax4(a1_0, a1_1), mx1b = vmax4(a1_2, a1_3);
        f32x4 mn1a = vmin4(a1_0, a1_1), mn1b = vmin4(a1_2, a1_3);
        size_t row0 = (nt48 + (size_t)(yt * 12 + ty * 2)) * 1536 + (size_t)(xt * 16 + tx * 2) * 32 + co0;
        size_t row1 = row0 + 1536;
        *(float2*)(pmax + row0)      = make_float2(fmaxf(mx0a.x, mx0a.y), fmaxf(mx1a.x, mx1a.y));
        *(float2*)(pmax + row0 + 32) = make_float2(fmaxf(mx0a.z, mx0a.w), fmaxf(mx1a.z, mx1a.w));
        *(float2*)(pmax + row1)      = make_float2(fmaxf(mx0b.x, mx0b.y), fmaxf(mx1b.x, mx1b.y));
        *(float2*)(pmax + row1 + 32) = make_float2(fmaxf(mx0b.z, mx0b.w), fmaxf(mx1b.z, mx1b.w));
        *(float2*)(pmin + row0)      = make_float2(fminf(mn0a.x, mn0a.y), fminf(mn1a.x, mn1a.y));
        *(float2*)(pmin + row0 + 32) = make_float2(fminf(mn0a.z, mn0a.w), fminf(mn1a.z, mn1a.w));
        *(float2*)(pmin + row1)      = make_float2(fminf(mn0b.x, mn0b.y), fminf(mn1b.x, mn1b.y));
        *(float2*)(pmin + row1 + 32) = make_float2(fminf(mn0b.z, mn0b.w), fminf(mn1b.z, mn1b.w));
    }

    // stats: reduce lanes sharing cg (stride 16/32 within wave), then LDS+global
    ls0 += __shfl_xor(ls0, 16, 64); ls0 += __shfl_xor(ls0, 32, 64);
    lq0 += __shfl_xor(lq0, 16, 64); lq0 += __shfl_xor(lq0, 32, 64);
    ls1 += __shfl_xor(ls1, 16, 64); ls1 += __shfl_xor(ls1, 32, 64);
    lq1 += __shfl_xor(lq1, 16, 64); lq1 += __shfl_xor(lq1, 32, 64);
    if ((tid & 63) < 16) {
        atomicAdd(&sst[co0 * 2], ls0);
        atomicAdd(&sst[co0 * 2 + 1], lq0);
        atomicAdd(&sst[co0 * 2 + 2], ls1);
        atomicAdd(&sst[co0 * 2 + 3], lq1);
    }
    __syncthreads();
    if (tid < 64) atomicAdd(&stats[tid], sst[tid]);
}

// -------- bnpool1b: pooled max/min -> BN affine + ReLU -> P2 hi/lo ----------
__global__ void bnpool1b(const float* __restrict__ pmax, const float* __restrict__ pmin,
                         const float* __restrict__ st, const float* __restrict__ gam,
                         const float* __restrict__ bet,
                         unsigned short* __restrict__ phi, unsigned short* __restrict__ plo) {
    int i = blockIdx.x * 256 + threadIdx.x;    // 589824 = 4*16*48*48*4
    int c8 = i & 3; int xo = (i >> 2) % 48; int yo = (i / 192) % 48;
    int t = (i / 9216) % 16; int n = i / 147456;
    size_t base = (((size_t)(n * 16 + t) * 48 + yo) * 48 + xo) * 32 + c8 * 8;
    union { unsigned short s[8]; uint4 v; } Uh, Ul;
    #pragma unroll
    for (int j = 0; j < 8; ++j) {
        int ch = c8 * 8 + j;
        float mean = st[ch * 2] * (1.f / 589824.f);
        float var  = st[ch * 2 + 1] * (1.f / 589824.f) - mean * mean;
        var = var < 0.f ? 0.f : var;
        float sc = gam[ch] / sqrtf(var + 1e-5f);
        float sh = bet[ch] - mean * sc;
        float pv = sc >= 0.f ? pmax[base + j] : pmin[base + j];
        float v = fmaxf(sc * pv + sh, 0.f);
        Uh.s[j] = f2bf(v);
        Ul.s[j] = f2bf(v - bf2f(Uh.s[j]));
    }
    size_t off = ((((size_t)n * 18 + t + 1) * 50 + yo + 1) * 52 + (xo + 1)) * 32 + c8 * 8;
    *(uint4*)(phi + off) = Uh.v;
    *(uint4*)(plo + off) = Ul.v;
}

// -------- conv2: 2-row x 32-co waves. Padded LDS [12][52][40] (stride 80B,
// conflict-free). Per step: 4 weight loads, 12 B ds_reads. -------------------
__launch_bounds__(256, 3)
__global__ void conv2k(const unsigned short* __restrict__ phi, const unsigned short* __restrict__ plo,
                       const unsigned short* __restrict__ w2p, const float* __restrict__ bias,
                       float* __restrict__ out, float* __restrict__ st) {
    __shared__ unsigned short tin[12 * 52 * 40];      // 24960 shorts = 49920 B
    float (*sred)[32] = (float (*)[32])(tin);          // alias: epilogue only
    float (*qred)[32] = (float (*)[32])(tin + 256);
    // XCD swizzle: 768 = 8 chunks x 96; chunk = (n, t-half).
    int b = blockIdx.x;
    int k8 = b & 7, i96 = b >> 3;
    int n = k8 >> 1, th = k8 & 1;
    int tt = i96 / 12; int y0 = (i96 - tt * 12) * 4;
    int t = th * 8 + tt;
    int w = threadIdx.x >> 6, lane = threadIdx.x & 63;
    int c = lane & 15, q = lane >> 4;
    int lrow = (w & 1) * 2, h2 = w >> 1;

    f32x4 acc[2][2][3];                                // [rr][mb'][xt]
    #pragma unroll
    for (int i = 0; i < 2; ++i)
        #pragma unroll
        for (int j = 0; j < 2; ++j)
            #pragma unroll
            for (int k = 0; k < 3; ++k) acc[i][j][k] = (f32x4)0.f;

    const int loff = h2 * 1024 + c * 32 + q * 8;       // weight lane offset (shorts)
    int tbo[2][3];                                     // B base offsets (shorts)
    #pragma unroll
    for (int rr = 0; rr < 2; ++rr)
        #pragma unroll
        for (int xt = 0; xt < 3; ++xt)
            tbo[rr][xt] = ((lrow + rr) * 52 + xt * 16 + c) * 40 + q * 8;

    #pragma unroll 1
    for (int kt = 0; kt < 3; ++kt) {
        const unsigned short* srch = phi + (size_t)(n * 18 + t + kt) * (50 * 52 * 32);
        const unsigned short* srcl = plo + (size_t)(n * 18 + t + kt) * (50 * 52 * 32);
        const unsigned short* wkt = w2p + kt * 36864;   // uniform (SGPR)
        __syncthreads();
        for (int i = threadIdx.x; i < 2496; i += 256) { // 12*52*4 16B-chunks
            int g = i & 3; int xx = (i >> 2) % 52; int rh = (i >> 2) / 52;
            int row = rh % 6; int h = rh / 6;
            const unsigned short* src = (h ? srcl : srch) + (size_t)(y0 + row) * 1664 + xx * 32 + g * 8;
            *(uint4*)(tin + (rh * 52 + xx) * 40 + (g << 3)) = *(const uint4*)src;
        }
        __syncthreads();
        #pragma unroll
        for (int ky = 0; ky < 3; ++ky) {
            #pragma unroll
            for (int kx = 0; kx < 3; ++kx) {
                const unsigned short* wb = wkt + (ky * 3 + kx) * 4096 + loff;
                short8 a0 = *(const short8*)(wb);
                short8 a1 = *(const short8*)(wb + 512);
                short8 l0 = *(const short8*)(wb + 2048);
                short8 l1 = *(const short8*)(wb + 2560);
                int off = (ky * 52 + kx) * 40;          // compile-time per step
                #pragma unroll
                for (int rr = 0; rr < 2; ++rr) {
                    short8 bh0 = *(const short8*)(tin + tbo[rr][0] + off);
                    short8 bl0 = *(const short8*)(tin + tbo[rr][0] + off + 12480);
                    short8 bh1 = *(const short8*)(tin + tbo[rr][1] + off);
                    short8 bl1 = *(const short8*)(tin + tbo[rr][1] + off + 12480);
                    short8 bh2 = *(const short8*)(tin + tbo[rr][2] + off);
                    short8 bl2 = *(const short8*)(tin + tbo[rr][2] + off + 12480);
                    MF(acc[rr][0][0], a0, bh0); MF(acc[rr][0][0], a0, bl0); MF(acc[rr][0][0], l0, bh0);
                    MF(acc[rr][0][1], a0, bh1); MF(acc[rr][0][1], a0, bl1); MF(acc[rr][0][1], l0, bh1);
                    MF(acc[rr][0][2], a0, bh2); MF(acc[rr][0][2], a0, bl2); MF(acc[rr][0][2], l0, bh2);
                    MF(acc[rr][1][0], a1, bh0); MF(acc[rr][1][0], a1, bl0); MF(acc[rr][1][0], l1, bh0);
                    MF(acc[rr][1][1], a1, bh1); MF(acc[rr][1][1], a1, bl1); MF(acc[rr][1][1], l1, bh1);
                    MF(acc[rr][1][2], a1, bh2); MF(acc[rr][1][2], a1, bl2); MF(acc[rr][1][2], l1, bh2);
                }
            }
        }
    }
    __syncthreads();        // fence: tin reads done before sred/qred alias writes
    #pragma unroll
    for (int mbp = 0; mbp < 2; ++mbp) {
        f32x4 bv = *(const f32x4*)(bias + h2 * 32 + mbp * 16 + q * 4);
        float s0 = 0.f, s1 = 0.f, s2 = 0.f, s3 = 0.f;
        float p0 = 0.f, p1 = 0.f, p2 = 0.f, p3 = 0.f;
        #pragma unroll
        for (int rr = 0; rr < 2; ++rr) {
            int y = y0 + lrow + rr;
            float* ob = out + (((size_t)(n * 16 + t) * 48) + y) * (48 * 64) + h2 * 32 + mbp * 16 + q * 4;
            #pragma unroll
            for (int xt = 0; xt < 3; ++xt) {
                f32x4 v = acc[rr][mbp][xt] + bv;
                *(f32x4*)(ob + (xt * 16 + c) * 64) = v;
                s0 += v.x; s1 += v.y; s2 += v.z; s3 += v.w;
                p0 += v.x * v.x; p1 += v.y * v.y; p2 += v.z * v.z; p3 += v.w * v.w;
            }
        }
        float sv[4] = {s0, s1, s2, s3}, qv[4] = {p0, p1, p2, p3};
        #pragma unroll
        for (int r = 0; r < 4; ++r) {
            float s = sv[r], q2 = qv[r];
            #pragma unroll
            for (int m = 1; m < 16; m <<= 1) { s += __shfl_xor(s, m, 64); q2 += __shfl_xor(q2, m, 64); }
            if (c == 0) { sred[w][mbp * 16 + q * 4 + r] = s; qred[w][mbp * 16 + q * 4 + r] = q2; }
        }
    }
    __syncthreads();
    if (threadIdx.x < 64) {
        int h = threadIdx.x >> 5, loc = threadIdx.x & 31;
        float s = sred[2 * h][loc] + sred[2 * h + 1][loc];
        float q2 = qred[2 * h][loc] + qred[2 * h + 1][loc];
        atomicAdd(&st[threadIdx.x * 2], s);
        atomicAdd(&st[threadIdx.x * 2 + 1], q2);
    }
}

// -------- bnpool2: conv2 out chan-last -> P3 [n][18][26][34][64] hi/lo ------
__global__ void bnpool2k(const float* __restrict__ cin, const float* __restrict__ st,
                         const float* __restrict__ gam, const float* __restrict__ bet,
                         unsigned short* __restrict__ phi, unsigned short* __restrict__ plo) {
    int i = blockIdx.x * 256 + threadIdx.x;    // 509184
    if (i >= 509184) return;
    int oc = i & 7; int xp = (i >> 3) % 34; int yp = (i / 272) % 26;
    int tp = (i / 7072) % 18; int n = i / 127296;
    union { unsigned short s[8]; uint4 v; } Uh, Ul;
    if (tp >= 1 && tp <= 16 && yp >= 1 && yp <= 24 && xp >= 1 && xp <= 24) {
        int t = tp - 1, yo = yp - 1, xo = xp - 1;
        const float* b0 = cin + ((((size_t)(n * 16 + t) * 48) + 2 * yo) * 48 + 2 * xo) * 64 + oc * 8;
        #pragma unroll
        for (int j = 0; j < 8; ++j) {
            int ch = oc * 8 + j;
            float mean = st[ch * 2] * (1.f / 147456.f);
            float var  = st[ch * 2 + 1] * (1.f / 147456.f) - mean * mean;
            var = var < 0.f ? 0.f : var;
            float sc = gam[ch] / sqrtf(var + 1e-5f);
            float sh = bet[ch] - mean * sc;
            float a  = b0[j] * sc + sh;
            float bb = b0[64 + j] * sc + sh;
            float c2 = b0[3072 + j] * sc + sh;
            float d  = b0[3136 + j] * sc + sh;
            float v = fmaxf(fmaxf(fmaxf(a, bb), fmaxf(c2, d)), 0.f);
            Uh.s[j] = f2bf(v);
            Ul.s[j] = f2bf(v - bf2f(Uh.s[j]));
        }
    } else {
        Uh.v = make_uint4(0, 0, 0, 0);
        Ul.v = make_uint4(0, 0, 0, 0);
    }
    size_t off = ((((size_t)n * 18 + tp) * 26 + yp) * 34 + xp) * 64 + oc * 8;
    *(uint4*)(phi + off) = Uh.v;
    *(uint4*)(plo + off) = Ul.v;
}

// -------- conv3: r13 body verbatim. 26-wide clamped tile (39936B), simple
// 1-row x 64-co waves (VGPR 52, no spill), lb(256,4). ------------------------
__launch_bounds__(256, 4)
__global__ void conv3k(const unsigned short* __restrict__ phi, const unsigned short* __restrict__ plo,
                       const unsigned short* __restrict__ w3p, const float* __restrict__ bias,
                       float* __restrict__ out, float* __restrict__ st) {
    __shared__ unsigned short tin[12 * 26 * 64];      // 19968 shorts = 39936 B
    float (*sred)[64] = (float (*)[64])(tin);          // alias: live after loop only
    float (*qred)[64] = (float (*)[64])(tin + 512);
    // XCD swizzle: 768 = 8 chunks x 96; chunk = (n, t-half), both cg inside.
    int b = blockIdx.x;
    int k8 = b & 7, i96 = b >> 3;
    int n = k8 >> 1, th = k8 & 1;
    int cg = i96 / 48; int r48 = i96 - cg * 48;
    int tt = r48 / 6;  int y0 = (r48 - tt * 6) * 4;
    int t = th * 8 + tt;
    int wv = threadIdx.x >> 6, lane = threadIdx.x & 63;
    int c = lane & 15, q = lane >> 4;
    int y = y0 + wv;

    f32x4 acc[4][2];
    #pragma unroll
    for (int i = 0; i < 4; ++i) { acc[i][0] = (f32x4)0.f; acc[i][1] = (f32x4)0.f; }

    const unsigned short* wsrc = w3p + (size_t)cg * 221184 + c * 32 + q * 8;

    #pragma unroll 1
    for (int kt = 0; kt < 3; ++kt) {
        const unsigned short* srch = phi + (size_t)(n * 18 + t + kt) * (26 * 34 * 64);
        const unsigned short* srcl = plo + (size_t)(n * 18 + t + kt) * (26 * 34 * 64);
        const unsigned short* wkt = wsrc + kt * 73728;
        __syncthreads();
        for (int i = threadIdx.x; i < 2496; i += 256) {     // 12*26*8 16B-chunks
            int g = i & 7; int xx = (i >> 3) % 26; int rh = (i >> 3) / 26;
            int row = rh % 6; int h = rh / 6;
            const unsigned short* src = (h ? srcl : srch) + (size_t)(y0 + row) * 2176 + xx * 64 + g * 8;
            *(uint4*)(tin + ((rh * 26 + xx) << 6) + ((g ^ (xx & 7)) << 3)) = *(const uint4*)src;
        }
        __syncthreads();
        #pragma unroll 1
        for (int ky = 0; ky < 3; ++ky) {
            int row = wv + ky;
            const unsigned short* wky = wkt + ky * 24576;
            #pragma unroll
            for (int kx = 0; kx < 3; ++kx) {
                #pragma unroll
                for (int kc = 0; kc < 2; ++kc) {
                    const unsigned short* wb = wky + kx * 8192 + kc * 2048;
                    short8 ah[4], al[4], bh[2], bl[2];
                    #pragma unroll
                    for (int mb = 0; mb < 4; ++mb) {
                        ah[mb] = *(const short8*)(wb + mb * 512);
                        al[mb] = *(const short8*)(wb + 4096 + mb * 512);
                    }
                    #pragma unroll
                    for (int xt = 0; xt < 2; ++xt) {
                        int xr = xt * 16 + kx + c;
                        int xx = xr > 25 ? 25 : xr;   // c>=8 @ xt=1: discarded cols, finite junk
                        int so = ((kc * 4 + q) ^ (xx & 7)) << 3;
                        bh[xt] = *(const short8*)(tin + ((row * 26 + xx) << 6) + so);
                        bl[xt] = *(const short8*)(tin + (((6 + row) * 26 + xx) << 6) + so);
                    }
                    #pragma unroll
                    for (int mb = 0; mb < 4; ++mb)
                        #pragma unroll
                        for (int xt = 0; xt < 2; ++xt) {
                            MF(acc[mb][xt], ah[mb], bh[xt]);
                            MF(acc[mb][xt], ah[mb], bl[xt]);
                            MF(acc[mb][xt], al[mb], bh[xt]);
                        }
                }
            }
        }
    }
    __syncthreads();        // fence: all tin reads done before sred/qred alias writes
    float* ob = out + (((size_t)(n * 16 + t) * 24) + y) * (24 * 128) + cg * 64;
    #pragma unroll
    for (int mb = 0; mb < 4; ++mb) {
        f32x4 bv = *(const f32x4*)(bias + cg * 64 + mb * 16 + q * 4);
        f32x4 v0 = acc[mb][0] + bv;
        f32x4 v1 = acc[mb][1] + bv;
        *(f32x4*)(ob + c * 128 + mb * 16 + q * 4) = v0;
        if (c < 8) *(f32x4*)(ob + (16 + c) * 128 + mb * 16 + q * 4) = v1;
        #pragma unroll
        for (int r = 0; r < 4; ++r) {
            float s  = v0[r] + (c < 8 ? v1[r] : 0.f);
            float q2 = v0[r] * v0[r] + (c < 8 ? v1[r] * v1[r] : 0.f);
            #pragma unroll
            for (int m = 1; m < 16; m <<= 1) { s += __shfl_xor(s, m, 64); q2 += __shfl_xor(q2, m, 64); }
            if (c == 0) { sred[wv][mb * 16 + q * 4 + r] = s; qred[wv][mb * 16 + q * 4 + r] = q2; }
        }
    }
    __syncthreads();
    if (threadIdx.x < 64) {
        int co = cg * 64 + threadIdx.x;
        float s = sred[0][threadIdx.x] + sred[1][threadIdx.x] + sred[2][threadIdx.x] + sred[3][threadIdx.x];
        float q2 = qred[0][threadIdx.x] + qred[1][threadIdx.x] + qred[2][threadIdx.x] + qred[3][threadIdx.x];
        atomicAdd(&st[co * 2], s);
        atomicAdd(&st[co * 2 + 1], q2);
    }
}

// -------- BN + ReLU + avgpool 6x6 (chan-last in) -> enc ---------------------
__global__ void bnavgk(const float* __restrict__ x, const float* __restrict__ st,
                       const float* __restrict__ gam, const float* __restrict__ bet,
                       float* __restrict__ enc) {
    int i = blockIdx.x * 256 + threadIdx.x;    // 131072
    int c = i & 127; int xo = (i >> 7) & 3; int yo = (i >> 9) & 3;
    int t = (i >> 11) & 15; int n = i >> 15;
    float mean = st[c * 2] * (1.f / 36864.f);
    float var  = st[c * 2 + 1] * (1.f / 36864.f) - mean * mean;
    var = var < 0.f ? 0.f : var;
    float sc = gam[c] / sqrtf(var + 1e-5f);
    float sh = bet[c] - mean * sc;
    const float* base = x + ((((size_t)(n * 16 + t) * 24) + yo * 6) * 24 + xo * 6) * 128 + c;
    float s = 0.f;
    #pragma unroll
    for (int wy = 0; wy < 6; ++wy)
        #pragma unroll
        for (int wx = 0; wx < 6; ++wx)
            s += fmaxf(base[(wy * 24 + wx) * 128] * sc + sh, 0.f);
    enc[(size_t)n * 32768 + (size_t)c * 256 + t * 16 + yo * 4 + xo] = s * (1.f / 36.f);
}

// -------- weight prepack kernels -------------------------------------------
__global__ void prep2k(const float* __restrict__ c2w, unsigned short* __restrict__ w2p) {
    int i = blockIdx.x * 256 + threadIdx.x;    // 110592
    if (i >= 110592) return;
    int ci = i & 31; int co = (i >> 5) & 63; int h = (i >> 11) & 1;
    int o = (i >> 12) % 9; int kt = i / 36864;
    int ky = o / 3, kx = o % 3;
    float w = c2w[(((size_t)(co * 32 + ci) * 3 + kt) * 3 + ky) * 3 + kx];
    unsigned short hi = f2bf(w);
    w2p[i] = h ? f2bf(w - bf2f(hi)) : hi;
}
__global__ void prep3k(const float* __restrict__ c3w, unsigned short* __restrict__ w3p) {
    int i = blockIdx.x * 256 + threadIdx.x;    // 442368
    if (i >= 442368) return;
    int cil = i & 31; int cop = (i >> 5) & 63; int kc = (i >> 11) & 1; int h = (i >> 12) & 1;
    int kx = (i >> 13) % 3; int ky = (i / 24576) % 3; int kt = (i / 73728) % 3; int cg = i / 221184;
    int ci = kc * 32 + cil; int co = cg * 64 + cop;
    float w = c3w[(((size_t)(co * 64 + ci) * 3 + kt) * 3 + ky) * 3 + kx];
    unsigned short hi = f2bf(w);
    w3p[i] = h ? f2bf(w - bf2f(hi)) : hi;
}
__global__ void prepwhhk(const float* __restrict__ whh, float* __restrict__ wt) {
    int i = blockIdx.x * 256 + threadIdx.x;    // 196608
    int g = i % 768, k = i / 768;
    wt[i] = whh[(size_t)g * 256 + k];
}

// -------- codebook transpose: cb[8192][256] -> cbT[256][8192] ---------------
__global__ void transck(const float* __restrict__ cb, float* __restrict__ cbT) {
    __shared__ float t[32][33];
    int bx = blockIdx.x & 255;
    int by = blockIdx.x >> 8;
    int ld = threadIdx.x & 31, lk = threadIdx.x >> 5;
    #pragma unroll
    for (int i = 0; i < 4; ++i) {
        int kl = lk + i * 8;
        t[kl][ld] = cb[(size_t)(bx * 32 + kl) * 256 + by * 32 + ld];
    }
    __syncthreads();
    #pragma unroll
    for (int i = 0; i < 4; ++i) {
        int dl = lk + i * 8;
        cbT[(size_t)(by * 32 + dl) * 8192 + bx * 32 + ld] = t[ld][dl];
    }
}

// -------- code norms in fp64 (ascending d, matches reference order) ---------
__global__ void cnormk(const float* __restrict__ cbT, double* __restrict__ cn2) {
    int k = blockIdx.x * 256 + threadIdx.x;    // 8192
    double s = 0.0;
    for (int d = 0; d < 256; ++d) {
        double c = (double)cbT[(size_t)d * 8192 + k];
        s += c * c;
    }
    cn2[k] = s;
}

// -------- proj init: feat = pb broadcast ------------------------------------
__global__ void projinitk(const float* __restrict__ pb, float* __restrict__ feat) {
    int i = blockIdx.x * 256 + threadIdx.x;    // 7168
    feat[i] = pb[i & 255];
}

// -------- proj (K-split x8): feat[r][d] += enc[r-chunk] . pw[d-chunk] -------
__global__ void projk(const float* __restrict__ enc, const float* __restrict__ pw,
                      float* __restrict__ feat) {
    int d = blockIdx.x & 255; int ch = blockIdx.x >> 8;    // 2048 blocks
    int k0 = ch * 4096;
    float acc[28];
    #pragma unroll
    for (int e = 0; e < 28; ++e) acc[e] = 0.f;
    const float* wrow = pw + (size_t)d * 32768 + k0;
    for (int k = threadIdx.x; k < 4096; k += 256) {
        float wv = wrow[k];
        #pragma unroll
        for (int e = 0; e < 28; ++e) acc[e] += enc[(size_t)e * 32768 + k0 + k] * wv;
    }
    __shared__ float red[4 * 28];
    #pragma unroll
    for (int e = 0; e < 28; ++e) {
        float v = acc[e];
        #pragma unroll
        for (int o = 32; o > 0; o >>= 1) v += __shfl_down(v, o, 64);
        if ((threadIdx.x & 63) == 0) red[(threadIdx.x >> 6) * 28 + e] = v;
    }
    __syncthreads();
    if (threadIdx.x < 28) {
        int e = threadIdx.x;
        int l = e >> 2, n = e & 3;
        float s = red[e] + red[28 + e] + red[56 + e] + red[84 + e];
        atomicAdd(&feat[(size_t)(n * 7 + l) * 256 + d], s);
    }
}

// -------- VQ: argmin over transposed codebook, fp64, 896 blocks -------------
__global__ void quantk(const float* __restrict__ feat, const float* __restrict__ cbT,
                       const double* __restrict__ cn2, unsigned long long* __restrict__ best) {
    int kc = blockIdx.x & 31, r = blockIdx.x >> 5;     // 896 = 32kc * 28r
    int k = kc * 256 + threadIdx.x;
    __shared__ float fs[256];
    fs[threadIdx.x] = feat[(size_t)r * 256 + threadIdx.x];
    __syncthreads();
    double dot = 0.0;
    for (int d = 0; d < 256; ++d)
        dot += (double)cbT[(size_t)d * 8192 + k] * (double)fs[d];
    float s = (float)(cn2[k] - 2.0 * dot);
    unsigned int bits = __float_as_uint(s);
    unsigned int key = (bits & 0x80000000u) ? ~bits : (bits | 0x80000000u);
    unsigned long long p = ((unsigned long long)key << 32) | (unsigned int)k;
    #pragma unroll
    for (int o = 32; o > 0; o >>= 1) {
        unsigned long long qv = __shfl_down(p, o, 64);
        if (qv < p) p = qv;
    }
    if ((threadIdx.x & 63) == 0) atomicMin(&best[r], p);
}

__global__ void gatherk(const unsigned long long* __restrict__ best,
                        const float* __restrict__ feat, const float* __restrict__ cb,
                        float* __restrict__ dout, float* __restrict__ quant,
                        float* __restrict__ acc) {
    int r = blockIdx.x;
    int d = threadIdx.x;
    int idx = (int)(best[r] & 0xFFFFFFFFull);
    float q = cb[(size_t)idx * 256 + d];
    quant[r * 256 + d] = q;
    dout[28 + r * 256 + d] = q;
    if (d == 0) dout[r] = (float)idx;
    float df = feat[r * 256 + d] - q;
    float v = df * df;
    #pragma unroll
    for (int o = 32; o > 0; o >>= 1) v += __shfl_down(v, o, 64);
    if ((d & 63) == 0) atomicAdd(&acc[0], v);
}

__global__ void gxk(const float* __restrict__ quant, const float* __restrict__ wih,
                    const float* __restrict__ bih, float* __restrict__ gx) {
    int o = blockIdx.x * 256 + threadIdx.x;
    int g = o % 768; int t = (o / 768) % 6; int n = o / (768 * 6);
    const float* q = quant + (size_t)(n * 7 + t) * 256;
    const float* w = wih + (size_t)g * 256;
    float s = bih[g];
    #pragma unroll 4
    for (int d = 0; d < 256; ++d) s += q[d] * w[d];
    gx[o] = s;
}

// -------- all 6 GRU steps in one kernel (block = batch b) -------------------
__global__ void gru_allk(const float* __restrict__ gx, const float* __restrict__ wt,
                         const float* __restrict__ bhh, const float* __restrict__ feat,
                         float* __restrict__ acc) {
    int b = blockIdx.x;        // 4
    int d = threadIdx.x;       // 256
    __shared__ float hs[256];
    hs[d] = 0.f;
    __syncthreads();
    float ctx = 0.f;
    for (int t = 0; t < 6; ++t) {
        float g0 = bhh[d], g1 = bhh[256 + d], g2 = bhh[512 + d];
        #pragma unroll 4
        for (int k = 0; k < 256; ++k) {
            float hv = hs[k];
            const float* wr = wt + (size_t)k * 768;
            g0 += wr[d] * hv; g1 += wr[256 + d] * hv; g2 += wr[512 + d] * hv;
        }
        const float* gxr = gx + (size_t)(b * 6 + t) * 768;
        float xr = gxr[d], xz = gxr[256 + d], xn = gxr[512 + d];
        float rr = 1.f / (1.f + expf(-(xr + g0)));
        float zz = 1.f / (1.f + expf(-(xz + g1)));
        float nn = tanhf(xn + rr * g2);
        float h2 = (1.f - zz) * nn + zz * hs[d];
        __syncthreads();
        hs[d] = h2;
        __syncthreads();
        float df = h2 - feat[(size_t)(b * 7 + t + 1) * 256 + d];
        ctx += df * df;
    }
    #pragma unroll
    for (int o = 32; o > 0; o >>= 1) ctx += __shfl_down(ctx, o, 64);
    if ((d & 63) == 0) atomicAdd(&acc[1], ctx);
}

__global__ void fink(const float* __restrict__ acc, float* __restrict__ dout) {
    float comm = acc[0] / 7168.f;
    float ctx  = acc[1] / 6144.f;
    dout[7196] = comm;
    dout[7197] = comm;
    dout[7198] = ctx;
    dout[7199] = comm + 0.25f * comm + 0.1f * ctx;
}

// ---------------------------------------------------------------------------
extern "C" void kernel_launch(void* const* d_in, const int* in_sizes, int n_in,
                              void* d_out, int out_size, void* d_ws, size_t ws_size,
                              hipStream_t stream) {
    (void)in_sizes; (void)n_in; (void)out_size; (void)ws_size;
    const float* x    = (const float*)d_in[0];
    const float* c1w  = (const float*)d_in[1];
    const float* c1b  = (const float*)d_in[2];
    const float* bn1g = (const float*)d_in[3];
    const float* bn1b = (const float*)d_in[4];
    const float* c2w  = (const float*)d_in[5];
    const float* c2b  = (const float*)d_in[6];
    const float* bn2g = (const float*)d_in[7];
    const float* bn2b = (const float*)d_in[8];
    const float* c3w  = (const float*)d_in[9];
    const float* c3b  = (const float*)d_in[10];
    const float* bn3g = (const float*)d_in[11];
    const float* bn3b = (const float*)d_in[12];
    const float* pw   = (const float*)d_in[13];
    const float* pb   = (const float*)d_in[14];
    const float* cb   = (const float*)d_in[15];
    const float* wih  = (const float*)d_in[16];
    const float* whh  = (const float*)d_in[17];
    const float* bih  = (const float*)d_in[18];
    const float* bhh  = (const float*)d_in[19];
    float* out = (float*)d_out;

    // ---- workspace layout (bytes) ----
    char* w = (char*)d_ws;
    float* A  = (float*)w;                         w += 75497472;   // conv2/3 outs; pmax/pmin + cbT alias
    float* PMAX = A;                                                // 18.87 MB (alias)
    float* PMIN = A + 4718592;                                      // 18.87 MB (alias)
    float* cbT = A;                                                 // 8 MB (alias, post-loop)
    double* cn2 = (double*)((char*)A + 8388608);                    // 64 KB (alias, post-loop)
    char*  SH = w;                                 w += 16293888;   // P3 hi/lo
    unsigned short* P3h = (unsigned short*)SH;
    unsigned short* P3l = (unsigned short*)(SH + 8146944);
    unsigned short* P2h = (unsigned short*)w;      w += 11980800;
    unsigned short* P2l = (unsigned short*)w;      w += 11980800;
    unsigned short* W2P = (unsigned short*)w;      w += 221184;
    unsigned short* W3P = (unsigned short*)w;      w += 884736;
    float* WT    = (float*)w;                      w += 786432;     // whh transposed [256][768]
    float* enc   = (float*)w;                      w += 3670016;
    float* feat  = (float*)w;                      w += 28672;
    float* quant = (float*)w;                      w += 28672;
    float* gx    = (float*)w;                      w += 73728;
    float* statsA = (float*)w;                     w += 21504;      // 21 x 256 floats
    float* acc    = (float*)w;                     w += 16;
    unsigned long long* best = (unsigned long long*)w;  w += 224;

    // ---- per-launch init ----
    hipMemsetAsync(P2h, 0, 11980800 * 2, stream);                  // P2 hi+lo pads
    hipMemsetAsync(statsA, 0, 21504 + 16, stream);                 // stats + acc
    hipMemsetAsync(best, 0xFF, 224, stream);
    prep2k<<<432, 256, 0, stream>>>(c2w, W2P);
    prep3k<<<1728, 256, 0, stream>>>(c3w, W3P);
    prepwhhk<<<768, 256, 0, stream>>>(whh, WT);

    for (int l = 0; l < 7; ++l) {
        float* st1 = statsA + (l * 3 + 0) * 256;
        float* st2 = statsA + (l * 3 + 1) * 256;
        float* st3 = statsA + (l * 3 + 2) * 256;
        conv1k<<<768, 256, 0, stream>>>(x, c1w, c1b, PMAX, PMIN, st1, l * 8);
        bnpool1b<<<2304, 256, 0, stream>>>(PMAX, PMIN, st1, bn1g, bn1b, P2h, P2l);
        conv2k<<<768, 256, 0, stream>>>(P2h, P2l, W2P, c2b, A, st2);
        bnpool2k<<<1989, 256, 0, stream>>>(A, st2, bn2g, bn2b, P3h, P3l);
        conv3k<<<768, 256, 0, stream>>>(P3h, P3l, W3P, c3b, A, st3);
        bnavgk<<<512, 256, 0, stream>>>(A, st3, bn3g, bn3b, enc + (size_t)l * 131072);
    }

    // A is free now: build transposed codebook + norms in its space
    transck<<<2048, 256, 0, stream>>>(cb, cbT);
    cnormk<<<32, 256, 0, stream>>>(cbT, cn2);
    projinitk<<<28, 256, 0, stream>>>(pb, feat);
    projk<<<2048, 256, 0, stream>>>(enc, pw, feat);
    quantk<<<896, 256, 0, stream>>>(feat, cbT, cn2, best);
    gatherk<<<28, 256, 0, stream>>>(best, feat, cb, out, quant, acc);
    gxk<<<72, 256, 0, stream>>>(quant, wih, bih, gx);
    gru_allk<<<4, 256, 0, stream>>>(gx, WT, bhh, feat, acc);
    fink<<<1, 1, 0, stream>>>(acc, out);
}

// Round 10
// 2207.660 us; speedup vs baseline: 1.0834x; 1.0005x over previous
//
#include <hip/hip_runtime.h>
#include <math.h>

// ---------------------------------------------------------------------------
// VQSign r18: remove conv3k's 33% junk MFMA. r17 (best, 2208.7us) computes a
// 24-wide row as 2x16 tiles; the xt=1 tile's c>=8 lanes are clamped junk
// (24 MFMA/step issued, 18 useful). r18 packs two rows' 8-col remainders into
// ONE 16-col tile (B col c -> row rp*2+(c>>3), x 16+(c&7)): wave wv does its
// full tile (row wv) + the packed remainder of row-pair wv>>1 for mb-pair
// (wv&1)*2 -> balanced 18 MFMA/step, zero waste, clamp gone, acc 32->24 VGPR.
// Per-output MFMA chains unchanged -> conv outputs bit-identical (only stats
// grouping shifts, same class as r15's conv2k which passed absmax 0).
// ah[mbr] dynamic indexing avoided via wave-uniform branch (rule #20).
// conv2k/projk/everything else: r17 verbatim.
// ---------------------------------------------------------------------------

typedef __attribute__((ext_vector_type(8))) short short8;
typedef __attribute__((ext_vector_type(4))) float f32x4;

__device__ inline unsigned short f2bf(float x) {
    unsigned int u = __float_as_uint(x);
    u += 0x7FFFu + ((u >> 16) & 1u);          // RNE
    return (unsigned short)(u >> 16);
}
__device__ inline float bf2f(unsigned short h) {
    return __uint_as_float(((unsigned int)h) << 16);
}
__device__ inline f32x4 vmax4(f32x4 a, f32x4 b) {
    return (f32x4){fmaxf(a.x, b.x), fmaxf(a.y, b.y), fmaxf(a.z, b.z), fmaxf(a.w, b.w)};
}
__device__ inline f32x4 vmin4(f32x4 a, f32x4 b) {
    return (f32x4){fminf(a.x, b.x), fminf(a.y, b.y), fminf(a.z, b.z), fminf(a.w, b.w)};
}

#define MF(d, a, b) d = __builtin_amdgcn_mfma_f32_16x16x32_bf16(a, b, d, 0, 0, 0)

// ---------------- conv1: fp32, LDS tile, pooled max/min chan-last out -------
#define C1LOADR(J) \
    f32x4 u = *(const f32x4*)(ip + (J) * 36); \
    f32x4 w4 = *(const f32x4*)(ip + (J) * 36 + 4); \
    f32x4 sA = u; \
    f32x4 sB = __builtin_shufflevector(u, w4, 1, 2, 3, 4); \
    f32x4 sC = __builtin_shufflevector(u, w4, 2, 3, 4, 5);
#define C1UPD0(I) a0_##I += wa0 * sA + wa1 * sB + wa2 * sC; a1_##I += wb0 * sA + wb1 * sB + wb2 * sC;
#define C1UPD1(I) a0_##I += wa3 * sA + wa4 * sB + wa5 * sC; a1_##I += wb3 * sA + wb4 * sB + wb5 * sC;
#define C1UPD2(I) a0_##I += wa6 * sA + wa7 * sB + wa8 * sC; a1_##I += wb6 * sA + wb7 * sB + wb8 * sC;

__launch_bounds__(256, 3)
__global__ void conv1k(const float* __restrict__ x, const float* __restrict__ wgt,
                       const float* __restrict__ bias, float* __restrict__ pmax,
                       float* __restrict__ pmin, float* __restrict__ stats, int t0) {
    int bb = blockIdx.x;
    int xt = bb % 3; int yt = (bb / 3) % 4; int t = (bb / 12) % 16; int n = bb / 192;
    int x0 = xt * 32, y0 = yt * 24;
    __shared__ float tile[9 * 936];           // [p=ci*3+kt][26 rows][36 (34 used)]
    __shared__ float wl[3456];                // [9p][32co][12 (9 used)] - b128 aligned
    __shared__ float sst[64];
    int tid = threadIdx.x;
    for (int i = tid; i < 3456; i += 256) {
        int idx = i % 12; int r = i / 12;
        int co = r & 31; int p = r >> 5;
        wl[i] = idx < 9 ? wgt[co * 81 + p * 9 + idx] : 0.f;
    }
    if (tid < 64) sst[tid] = 0.f;
    for (int i = tid; i < 7956; i += 256) {
        int p = i / 884; int rem = i % 884;
        int r = rem / 34, cl = rem % 34;
        int ci = p / 3, kt = p % 3;
        int lt = t + kt - 1;
        int yy = y0 + r - 1, xx = x0 + cl - 1;
        float v = 0.f;
        if (lt >= 0 && lt <= 15 && yy >= 0 && yy < 96 && xx >= 0 && xx < 96)
            v = x[((size_t)(n * 3 + ci) * 64 + (t0 + lt)) * 9216 + yy * 96 + cl + x0 - 1];
        tile[p * 936 + r * 36 + cl] = v;
    }
    __syncthreads();

    int cg = tid & 15;            // lane-fixed channel pair
    int co0 = cg * 2;
    float bv0 = bias[co0], bv1 = bias[co0 + 1];
    float ls0 = 0.f, lq0 = 0.f, ls1 = 0.f, lq1 = 0.f;
    size_t nt48 = (size_t)(n * 16 + t) * 48;

    #pragma unroll 1
    for (int rr = 0; rr < 3; ++rr) {
        int sp = rr * 16 + (tid >> 4);
        int tx = sp & 7, ty = sp >> 3;
        f32x4 a0_0 = (f32x4)bv0, a0_1 = (f32x4)bv0, a0_2 = (f32x4)bv0, a0_3 = (f32x4)bv0;
        f32x4 a1_0 = (f32x4)bv1, a1_1 = (f32x4)bv1, a1_2 = (f32x4)bv1, a1_3 = (f32x4)bv1;

        #pragma unroll 1
        for (int p = 0; p < 9; ++p) {
            const float* wpk = wl + ((p * 32 + co0) * 12);
            f32x4 wv0 = *(const f32x4*)(wpk);
            f32x4 wv1 = *(const f32x4*)(wpk + 4);
            f32x4 wv2 = *(const f32x4*)(wpk + 8);
            f32x4 wv3 = *(const f32x4*)(wpk + 12);
            f32x4 wv4 = *(const f32x4*)(wpk + 16);
            f32x4 wv5 = *(const f32x4*)(wpk + 20);
            float wa0 = wv0.x, wa1 = wv0.y, wa2 = wv0.z, wa3 = wv0.w;
            float wa4 = wv1.x, wa5 = wv1.y, wa6 = wv1.z, wa7 = wv1.w;
            float wa8 = wv2.x;
            float wb0 = wv3.x, wb1 = wv3.y, wb2 = wv3.z, wb3 = wv3.w;
            float wb4 = wv4.x, wb5 = wv4.y, wb6 = wv4.z, wb7 = wv4.w;
            float wb8 = wv5.x;
            const float* ip = tile + p * 936 + (ty * 4) * 36 + tx * 4;
            { C1LOADR(0) C1UPD0(0) }
            { C1LOADR(1) C1UPD0(1) C1UPD1(0) }
            { C1LOADR(2) C1UPD0(2) C1UPD1(1) C1UPD2(0) }
            { C1LOADR(3) C1UPD0(3) C1UPD1(2) C1UPD2(1) }
            { C1LOADR(4) C1UPD1(3) C1UPD2(2) }
            { C1LOADR(5) C1UPD2(3) }
        }

        // stats (full-res, pre-pool), accumulate in registers across rounds
        f32x4 s4 = a0_0 + a0_1 + a0_2 + a0_3;
        ls0 += s4.x + s4.y + s4.z + s4.w;
        f32x4 q4 = a0_0 * a0_0 + a0_1 * a0_1 + a0_2 * a0_2 + a0_3 * a0_3;
        lq0 += q4.x + q4.y + q4.z + q4.w;
        f32x4 s5 = a1_0 + a1_1 + a1_2 + a1_3;
        ls1 += s5.x + s5.y + s5.z + s5.w;
        f32x4 q5 = a1_0 * a1_0 + a1_1 * a1_1 + a1_2 * a1_2 + a1_3 * a1_3;
        lq1 += q5.x + q5.y + q5.z + q5.w;

        // 2x2 max/min pool in-register, direct coalesced stores
        f32x4 mx0a = vmax4(a0_0, a0_1), mx0b = vmax4(a0_2, a0_3);
        f32x4 mn0a = vmin4(a0_0, a0_1), mn0b = vmin4(a0_2, a0_3);
        f32x4 mx1a = vmax4(a1_0, a1_1), mx1b = vmax4(a1_2, a1_3);
        f32x4 mn1a = vmin4(a1_0, a1_1), mn1b = vmin4(a1_2, a1_3);
        size_t row0 = (nt48 + (size_t)(yt * 12 + ty * 2)) * 1536 + (size_t)(xt * 16 + tx * 2) * 32 + co0;
        size_t row1 = row0 + 1536;
        *(float2*)(pmax + row0)      = make_float2(fmaxf(mx0a.x, mx0a.y), fmaxf(mx1a.x, mx1a.y));
        *(float2*)(pmax + row0 + 32) = make_float2(fmaxf(mx0a.z, mx0a.w), fmaxf(mx1a.z, mx1a.w));
        *(float2*)(pmax + row1)      = make_float2(fmaxf(mx0b.x, mx0b.y), fmaxf(mx1b.x, mx1b.y));
        *(float2*)(pmax + row1 + 32) = make_float2(fmaxf(mx0b.z, mx0b.w), fmaxf(mx1b.z, mx1b.w));
        *(float2*)(pmin + row0)      = make_float2(fminf(mn0a.x, mn0a.y), fminf(mn1a.x, mn1a.y));
        *(float2*)(pmin + row0 + 32) = make_float2(fminf(mn0a.z, mn0a.w), fminf(mn1a.z, mn1a.w));
        *(float2*)(pmin + row1)      = make_float2(fminf(mn0b.x, mn0b.y), fminf(mn1b.x, mn1b.y));
        *(float2*)(pmin + row1 + 32) = make_float2(fminf(mn0b.z, mn0b.w), fminf(mn1b.z, mn1b.w));
    }

    // stats: reduce lanes sharing cg (stride 16/32 within wave), then LDS+global
    ls0 += __shfl_xor(ls0, 16, 64); ls0 += __shfl_xor(ls0, 32, 64);
    lq0 += __shfl_xor(lq0, 16, 64); lq0 += __shfl_xor(lq0, 32, 64);
    ls1 += __shfl_xor(ls1, 16, 64); ls1 += __shfl_xor(ls1, 32, 64);
    lq1 += __shfl_xor(lq1, 16, 64); lq1 += __shfl_xor(lq1, 32, 64);
    if ((tid & 63) < 16) {
        atomicAdd(&sst[co0 * 2], ls0);
        atomicAdd(&sst[co0 * 2 + 1], lq0);
        atomicAdd(&sst[co0 * 2 + 2], ls1);
        atomicAdd(&sst[co0 * 2 + 3], lq1);
    }
    __syncthreads();
    if (tid < 64) atomicAdd(&stats[tid], sst[tid]);
}

// -------- bnpool1b: pooled max/min -> BN affine + ReLU -> P2 hi/lo ----------
__global__ void bnpool1b(const float* __restrict__ pmax, const float* __restrict__ pmin,
                         const float* __restrict__ st, const float* __restrict__ gam,
                         const float* __restrict__ bet,
                         unsigned short* __restrict__ phi, unsigned short* __restrict__ plo) {
    int i = blockIdx.x * 256 + threadIdx.x;    // 589824 = 4*16*48*48*4
    int c8 = i & 3; int xo = (i >> 2) % 48; int yo = (i / 192) % 48;
    int t = (i / 9216) % 16; int n = i / 147456;
    size_t base = (((size_t)(n * 16 + t) * 48 + yo) * 48 + xo) * 32 + c8 * 8;
    union { unsigned short s[8]; uint4 v; } Uh, Ul;
    #pragma unroll
    for (int j = 0; j < 8; ++j) {
        int ch = c8 * 8 + j;
        float mean = st[ch * 2] * (1.f / 589824.f);
        float var  = st[ch * 2 + 1] * (1.f / 589824.f) - mean * mean;
        var = var < 0.f ? 0.f : var;
        float sc = gam[ch] / sqrtf(var + 1e-5f);
        float sh = bet[ch] - mean * sc;
        float pv = sc >= 0.f ? pmax[base + j] : pmin[base + j];
        float v = fmaxf(sc * pv + sh, 0.f);
        Uh.s[j] = f2bf(v);
        Ul.s[j] = f2bf(v - bf2f(Uh.s[j]));
    }
    size_t off = ((((size_t)n * 18 + t + 1) * 50 + yo + 1) * 52 + (xo + 1)) * 32 + c8 * 8;
    *(uint4*)(phi + off) = Uh.v;
    *(uint4*)(plo + off) = Ul.v;
}

// -------- conv2: 2-row x 32-co waves. Padded LDS [12][52][40] (stride 80B,
// conflict-free). Per step: 4 weight loads, 12 B ds_reads. -------------------
__launch_bounds__(256, 3)
__global__ void conv2k(const unsigned short* __restrict__ phi, const unsigned short* __restrict__ plo,
                       const unsigned short* __restrict__ w2p, const float* __restrict__ bias,
                       float* __restrict__ out, float* __restrict__ st) {
    __shared__ unsigned short tin[12 * 52 * 40];      // 24960 shorts = 49920 B
    float (*sred)[32] = (float (*)[32])(tin);          // alias: epilogue only
    float (*qred)[32] = (float (*)[32])(tin + 256);
    // XCD swizzle: 768 = 8 chunks x 96; chunk = (n, t-half).
    int b = blockIdx.x;
    int k8 = b & 7, i96 = b >> 3;
    int n = k8 >> 1, th = k8 & 1;
    int tt = i96 / 12; int y0 = (i96 - tt * 12) * 4;
    int t = th * 8 + tt;
    int w = threadIdx.x >> 6, lane = threadIdx.x & 63;
    int c = lane & 15, q = lane >> 4;
    int lrow = (w & 1) * 2, h2 = w >> 1;

    f32x4 acc[2][2][3];                                // [rr][mb'][xt]
    #pragma unroll
    for (int i = 0; i < 2; ++i)
        #pragma unroll
        for (int j = 0; j < 2; ++j)
            #pragma unroll
            for (int k = 0; k < 3; ++k) acc[i][j][k] = (f32x4)0.f;

    const int loff = h2 * 1024 + c * 32 + q * 8;       // weight lane offset (shorts)
    int tbo[2][3];                                     // B base offsets (shorts)
    #pragma unroll
    for (int rr = 0; rr < 2; ++rr)
        #pragma unroll
        for (int xt = 0; xt < 3; ++xt)
            tbo[rr][xt] = ((lrow + rr) * 52 + xt * 16 + c) * 40 + q * 8;

    #pragma unroll 1
    for (int kt = 0; kt < 3; ++kt) {
        const unsigned short* srch = phi + (size_t)(n * 18 + t + kt) * (50 * 52 * 32);
        const unsigned short* srcl = plo + (size_t)(n * 18 + t + kt) * (50 * 52 * 32);
        const unsigned short* wkt = w2p + kt * 36864;   // uniform (SGPR)
        __syncthreads();
        for (int i = threadIdx.x; i < 2496; i += 256) { // 12*52*4 16B-chunks
            int g = i & 3; int xx = (i >> 2) % 52; int rh = (i >> 2) / 52;
            int row = rh % 6; int h = rh / 6;
            const unsigned short* src = (h ? srcl : srch) + (size_t)(y0 + row) * 1664 + xx * 32 + g * 8;
            *(uint4*)(tin + (rh * 52 + xx) * 40 + (g << 3)) = *(const uint4*)src;
        }
        __syncthreads();
        #pragma unroll
        for (int ky = 0; ky < 3; ++ky) {
            #pragma unroll
            for (int kx = 0; kx < 3; ++kx) {
                const unsigned short* wb = wkt + (ky * 3 + kx) * 4096 + loff;
                short8 a0 = *(const short8*)(wb);
                short8 a1 = *(const short8*)(wb + 512);
                short8 l0 = *(const short8*)(wb + 2048);
                short8 l1 = *(const short8*)(wb + 2560);
                int off = (ky * 52 + kx) * 40;          // compile-time per step
                #pragma unroll
                for (int rr = 0; rr < 2; ++rr) {
                    short8 bh0 = *(const short8*)(tin + tbo[rr][0] + off);
                    short8 bl0 = *(const short8*)(tin + tbo[rr][0] + off + 12480);
                    short8 bh1 = *(const short8*)(tin + tbo[rr][1] + off);
                    short8 bl1 = *(const short8*)(tin + tbo[rr][1] + off + 12480);
                    short8 bh2 = *(const short8*)(tin + tbo[rr][2] + off);
                    short8 bl2 = *(const short8*)(tin + tbo[rr][2] + off + 12480);
                    MF(acc[rr][0][0], a0, bh0); MF(acc[rr][0][0], a0, bl0); MF(acc[rr][0][0], l0, bh0);
                    MF(acc[rr][0][1], a0, bh1); MF(acc[rr][0][1], a0, bl1); MF(acc[rr][0][1], l0, bh1);
                    MF(acc[rr][0][2], a0, bh2); MF(acc[rr][0][2], a0, bl2); MF(acc[rr][0][2], l0, bh2);
                    MF(acc[rr][1][0], a1, bh0); MF(acc[rr][1][0], a1, bl0); MF(acc[rr][1][0], l1, bh0);
                    MF(acc[rr][1][1], a1, bh1); MF(acc[rr][1][1], a1, bl1); MF(acc[rr][1][1], l1, bh1);
                    MF(acc[rr][1][2], a1, bh2); MF(acc[rr][1][2], a1, bl2); MF(acc[rr][1][2], l1, bh2);
                }
            }
        }
    }
    __syncthreads();        // fence: tin reads done before sred/qred alias writes
    #pragma unroll
    for (int mbp = 0; mbp < 2; ++mbp) {
        f32x4 bv = *(const f32x4*)(bias + h2 * 32 + mbp * 16 + q * 4);
        float s0 = 0.f, s1 = 0.f, s2 = 0.f, s3 = 0.f;
        float p0 = 0.f, p1 = 0.f, p2 = 0.f, p3 = 0.f;
        #pragma unroll
        for (int rr = 0; rr < 2; ++rr) {
            int y = y0 + lrow + rr;
            float* ob = out + (((size_t)(n * 16 + t) * 48) + y) * (48 * 64) + h2 * 32 + mbp * 16 + q * 4;
            #pragma unroll
            for (int xt = 0; xt < 3; ++xt) {
                f32x4 v = acc[rr][mbp][xt] + bv;
                *(f32x4*)(ob + (xt * 16 + c) * 64) = v;
                s0 += v.x; s1 += v.y; s2 += v.z; s3 += v.w;
                p0 += v.x * v.x; p1 += v.y * v.y; p2 += v.z * v.z; p3 += v.w * v.w;
            }
        }
        float sv[4] = {s0, s1, s2, s3}, qv[4] = {p0, p1, p2, p3};
        #pragma unroll
        for (int r = 0; r < 4; ++r) {
            float s = sv[r], q2 = qv[r];
            #pragma unroll
            for (int m = 1; m < 16; m <<= 1) { s += __shfl_xor(s, m, 64); q2 += __shfl_xor(q2, m, 64); }
            if (c == 0) { sred[w][mbp * 16 + q * 4 + r] = s; qred[w][mbp * 16 + q * 4 + r] = q2; }
        }
    }
    __syncthreads();
    if (threadIdx.x < 64) {
        int h = threadIdx.x >> 5, loc = threadIdx.x & 31;
        float s = sred[2 * h][loc] + sred[2 * h + 1][loc];
        float q2 = qred[2 * h][loc] + qred[2 * h + 1][loc];
        atomicAdd(&st[threadIdx.x * 2], s);
        atomicAdd(&st[threadIdx.x * 2 + 1], q2);
    }
}

// -------- bnpool2: conv2 out chan-last -> P3 [n][18][26][34][64] hi/lo ------
__global__ void bnpool2k(const float* __restrict__ cin, const float* __restrict__ st,
                         const float* __restrict__ gam, const float* __restrict__ bet,
                         unsigned short* __restrict__ phi, unsigned short* __restrict__ plo) {
    int i = blockIdx.x * 256 + threadIdx.x;    // 509184
    if (i >= 509184) return;
    int oc = i & 7; int xp = (i >> 3) % 34; int yp = (i / 272) % 26;
    int tp = (i / 7072) % 18; int n = i / 127296;
    union { unsigned short s[8]; uint4 v; } Uh, Ul;
    if (tp >= 1 && tp <= 16 && yp >= 1 && yp <= 24 && xp >= 1 && xp <= 24) {
        int t = tp - 1, yo = yp - 1, xo = xp - 1;
        const float* b0 = cin + ((((size_t)(n * 16 + t) * 48) + 2 * yo) * 48 + 2 * xo) * 64 + oc * 8;
        #pragma unroll
        for (int j = 0; j < 8; ++j) {
            int ch = oc * 8 + j;
            float mean = st[ch * 2] * (1.f / 147456.f);
            float var  = st[ch * 2 + 1] * (1.f / 147456.f) - mean * mean;
            var = var < 0.f ? 0.f : var;
            float sc = gam[ch] / sqrtf(var + 1e-5f);
            float sh = bet[ch] - mean * sc;
            float a  = b0[j] * sc + sh;
            float bb = b0[64 + j] * sc + sh;
            float c2 = b0[3072 + j] * sc + sh;
            float d  = b0[3136 + j] * sc + sh;
            float v = fmaxf(fmaxf(fmaxf(a, bb), fmaxf(c2, d)), 0.f);
            Uh.s[j] = f2bf(v);
            Ul.s[j] = f2bf(v - bf2f(Uh.s[j]));
        }
    } else {
        Uh.v = make_uint4(0, 0, 0, 0);
        Ul.v = make_uint4(0, 0, 0, 0);
    }
    size_t off = ((((size_t)n * 18 + tp) * 26 + yp) * 34 + xp) * 64 + oc * 8;
    *(uint4*)(phi + off) = Uh.v;
    *(uint4*)(plo + off) = Ul.v;
}

// -------- conv3: r13 structure + packed row-pair remainders. Wave wv: full
// 16-col tile of row wv (mb 0..3) + packed remainder tile (cols 16-23 of rows
// (wv>>1)*2..+1, B col c -> row +(c>>3), x 16+(c&7)) for mbs (wv&1)*2..+1.
// 18 MFMA/step (was 24), no clamp junk. ------------------------------------
__launch_bounds__(256, 4)
__global__ void conv3k(const unsigned short* __restrict__ phi, const unsigned short* __restrict__ plo,
                       const unsigned short* __restrict__ w3p, const float* __restrict__ bias,
                       float* __restrict__ out, float* __restrict__ st) {
    __shared__ unsigned short tin[12 * 26 * 64];      // 19968 shorts = 39936 B
    float (*sred)[64] = (float (*)[64])(tin);          // alias: live after loop only
    float (*qred)[64] = (float (*)[64])(tin + 512);
    // XCD swizzle: 768 = 8 chunks x 96; chunk = (n, t-half), both cg inside.
    int b = blockIdx.x;
    int k8 = b & 7, i96 = b >> 3;
    int n = k8 >> 1, th = k8 & 1;
    int cg = i96 / 48; int r48 = i96 - cg * 48;
    int tt = r48 / 6;  int y0 = (r48 - tt * 6) * 4;
    int t = th * 8 + tt;
    int wv = threadIdx.x >> 6, lane = threadIdx.x & 63;
    int c = lane & 15, q = lane >> 4;
    int y = y0 + wv;
    int rp = wv >> 1;              // remainder row-pair this wave owns
    int mbr = (wv & 1) * 2;        // remainder mb base (uniform per wave)
    int rbase = rp * 2 + (c >> 3); // remainder row (pre-ky), per lane
    int xrc = 16 + (c & 7);        // remainder x (pre-kx), per lane

    f32x4 accF[4];                 // full tile, row y, cols 0-15
    f32x4 accR[2];                 // packed remainder, mbs mbr..mbr+1
    #pragma unroll
    for (int i = 0; i < 4; ++i) accF[i] = (f32x4)0.f;
    accR[0] = (f32x4)0.f; accR[1] = (f32x4)0.f;

    const unsigned short* wsrc = w3p + (size_t)cg * 221184 + c * 32 + q * 8;

    #pragma unroll 1
    for (int kt = 0; kt < 3; ++kt) {
        const unsigned short* srch = phi + (size_t)(n * 18 + t + kt) * (26 * 34 * 64);
        const unsigned short* srcl = plo + (size_t)(n * 18 + t + kt) * (26 * 34 * 64);
        const unsigned short* wkt = wsrc + kt * 73728;
        __syncthreads();
        for (int i = threadIdx.x; i < 2496; i += 256) {     // 12*26*8 16B-chunks
            int g = i & 7; int xx = (i >> 3) % 26; int rh = (i >> 3) / 26;
            int row = rh % 6; int h = rh / 6;
            const unsigned short* src = (h ? srcl : srch) + (size_t)(y0 + row) * 2176 + xx * 64 + g * 8;
            *(uint4*)(tin + ((rh * 26 + xx) << 6) + ((g ^ (xx & 7)) << 3)) = *(const uint4*)src;
        }
        __syncthreads();
        #pragma unroll 1
        for (int ky = 0; ky < 3; ++ky) {
            int rowF = wv + ky;
            int rowR = rbase + ky;
            const unsigned short* wky = wkt + ky * 24576;
            #pragma unroll
            for (int kx = 0; kx < 3; ++kx) {
                #pragma unroll
                for (int kc = 0; kc < 2; ++kc) {
                    const unsigned short* wb = wky + kx * 8192 + kc * 2048;
                    short8 ah[4], al[4];
                    #pragma unroll
                    for (int mb = 0; mb < 4; ++mb) {
                        ah[mb] = *(const short8*)(wb + mb * 512);
                        al[mb] = *(const short8*)(wb + 4096 + mb * 512);
                    }
                    // full tile B (cols 0-15): x = kx + c <= 17, no clamp
                    int xF = kx + c;
                    int soF = ((kc * 4 + q) ^ (xF & 7)) << 3;
                    short8 bhF = *(const short8*)(tin + ((rowF * 26 + xF) << 6) + soF);
                    short8 blF = *(const short8*)(tin + (((6 + rowF) * 26 + xF) << 6) + soF);
                    // packed remainder B: row rbase+ky, x = 16+kx+(c&7) <= 25
                    int xR = xrc + kx;
                    int soR = ((kc * 4 + q) ^ (xR & 7)) << 3;
                    short8 bhR = *(const short8*)(tin + ((rowR * 26 + xR) << 6) + soR);
                    short8 blR = *(const short8*)(tin + (((6 + rowR) * 26 + xR) << 6) + soR);
                    #pragma unroll
                    for (int mb = 0; mb < 4; ++mb) {
                        MF(accF[mb], ah[mb], bhF);
                        MF(accF[mb], ah[mb], blF);
                        MF(accF[mb], al[mb], bhF);
                    }
                    if ((wv & 1) == 0) {       // wave-uniform: mbr = 0
                        MF(accR[0], ah[0], bhR); MF(accR[0], ah[0], blR); MF(accR[0], al[0], bhR);
                        MF(accR[1], ah[1], bhR); MF(accR[1], ah[1], blR); MF(accR[1], al[1], bhR);
                    } else {                   // mbr = 2
                        MF(accR[0], ah[2], bhR); MF(accR[0], ah[2], blR); MF(accR[0], al[2], bhR);
                        MF(accR[1], ah[3], bhR); MF(accR[1], ah[3], blR); MF(accR[1], al[3], bhR);
                    }
                }
            }
        }
    }
    __syncthreads();        // fence: all tin reads done before sred/qred alias writes
    // remainder epilogue: row y0+rbase, col 16+(c&7), co cg*64+(mbr+j)*16+q*4
    f32x4 bvRa = *(const f32x4*)(bias + cg * 64 + mbr * 16 + q * 4);
    f32x4 bvRb = *(const f32x4*)(bias + cg * 64 + (mbr + 1) * 16 + q * 4);
    f32x4 vRa = accR[0] + bvRa;
    f32x4 vRb = accR[1] + bvRb;
    {
        float* obr = out + (((size_t)(n * 16 + t) * 24) + y0 + rbase) * (24 * 128)
                   + cg * 64 + xrc * 128 + q * 4;
        *(f32x4*)(obr + mbr * 16) = vRa;
        *(f32x4*)(obr + (mbr + 1) * 16) = vRb;
    }
    float* ob = out + (((size_t)(n * 16 + t) * 24) + y) * (24 * 128) + cg * 64;
    #pragma unroll
    for (int mb = 0; mb < 4; ++mb) {
        f32x4 bv = *(const f32x4*)(bias + cg * 64 + mb * 16 + q * 4);
        f32x4 v0 = accF[mb] + bv;
        *(f32x4*)(ob + c * 128 + mb * 16 + q * 4) = v0;
        #pragma unroll
        for (int r = 0; r < 4; ++r) {
            float ra = (mb == mbr) ? vRa[r] : (mb == mbr + 1) ? vRb[r] : 0.f;
            float s  = v0[r] + ra;
            float q2 = v0[r] * v0[r] + ra * ra;
            #pragma unroll
            for (int m = 1; m < 16; m <<= 1) { s += __shfl_xor(s, m, 64); q2 += __shfl_xor(q2, m, 64); }
            if (c == 0) { sred[wv][mb * 16 + q * 4 + r] = s; qred[wv][mb * 16 + q * 4 + r] = q2; }
        }
    }
    __syncthreads();
    if (threadIdx.x < 64) {
        int co = cg * 64 + threadIdx.x;
        float s = sred[0][threadIdx.x] + sred[1][threadIdx.x] + sred[2][threadIdx.x] + sred[3][threadIdx.x];
        float q2 = qred[0][threadIdx.x] + qred[1][threadIdx.x] + qred[2][threadIdx.x] + qred[3][threadIdx.x];
        atomicAdd(&st[co * 2], s);
        atomicAdd(&st[co * 2 + 1], q2);
    }
}

// -------- BN + ReLU + avgpool 6x6 (chan-last in) -> enc ---------------------
__global__ void bnavgk(const float* __restrict__ x, const float* __restrict__ st,
                       const float* __restrict__ gam, const float* __restrict__ bet,
                       float* __restrict__ enc) {
    int i = blockIdx.x * 256 + threadIdx.x;    // 131072
    int c = i & 127; int xo = (i >> 7) & 3; int yo = (i >> 9) & 3;
    int t = (i >> 11) & 15; int n = i >> 15;
    float mean = st[c * 2] * (1.f / 36864.f);
    float var  = st[c * 2 + 1] * (1.f / 36864.f) - mean * mean;
    var = var < 0.f ? 0.f : var;
    float sc = gam[c] / sqrtf(var + 1e-5f);
    float sh = bet[c] - mean * sc;
    const float* base = x + ((((size_t)(n * 16 + t) * 24) + yo * 6) * 24 + xo * 6) * 128 + c;
    float s = 0.f;
    #pragma unroll
    for (int wy = 0; wy < 6; ++wy)
        #pragma unroll
        for (int wx = 0; wx < 6; ++wx)
            s += fmaxf(base[(wy * 24 + wx) * 128] * sc + sh, 0.f);
    enc[(size_t)n * 32768 + (size_t)c * 256 + t * 16 + yo * 4 + xo] = s * (1.f / 36.f);
}

// -------- weight prepack kernels -------------------------------------------
__global__ void prep2k(const float* __restrict__ c2w, unsigned short* __restrict__ w2p) {
    int i = blockIdx.x * 256 + threadIdx.x;    // 110592
    if (i >= 110592) return;
    int ci = i & 31; int co = (i >> 5) & 63; int h = (i >> 11) & 1;
    int o = (i >> 12) % 9; int kt = i / 36864;
    int ky = o / 3, kx = o % 3;
    float w = c2w[(((size_t)(co * 32 + ci) * 3 + kt) * 3 + ky) * 3 + kx];
    unsigned short hi = f2bf(w);
    w2p[i] = h ? f2bf(w - bf2f(hi)) : hi;
}
__global__ void prep3k(const float* __restrict__ c3w, unsigned short* __restrict__ w3p) {
    int i = blockIdx.x * 256 + threadIdx.x;    // 442368
    if (i >= 442368) return;
    int cil = i & 31; int cop = (i >> 5) & 63; int kc = (i >> 11) & 1; int h = (i >> 12) & 1;
    int kx = (i >> 13) % 3; int ky = (i / 24576) % 3; int kt = (i / 73728) % 3; int cg = i / 221184;
    int ci = kc * 32 + cil; int co = cg * 64 + cop;
    float w = c3w[(((size_t)(co * 64 + ci) * 3 + kt) * 3 + ky) * 3 + kx];
    unsigned short hi = f2bf(w);
    w3p[i] = h ? f2bf(w - bf2f(hi)) : hi;
}
__global__ void prepwhhk(const float* __restrict__ whh, float* __restrict__ wt) {
    int i = blockIdx.x * 256 + threadIdx.x;    // 196608
    int g = i % 768, k = i / 768;
    wt[i] = whh[(size_t)g * 256 + k];
}

// -------- codebook transpose: cb[8192][256] -> cbT[256][8192] ---------------
__global__ void transck(const float* __restrict__ cb, float* __restrict__ cbT) {
    __shared__ float t[32][33];
    int bx = blockIdx.x & 255;
    int by = blockIdx.x >> 8;
    int ld = threadIdx.x & 31, lk = threadIdx.x >> 5;
    #pragma unroll
    for (int i = 0; i < 4; ++i) {
        int kl = lk + i * 8;
        t[kl][ld] = cb[(size_t)(bx * 32 + kl) * 256 + by * 32 + ld];
    }
    __syncthreads();
    #pragma unroll
    for (int i = 0; i < 4; ++i) {
        int dl = lk + i * 8;
        cbT[(size_t)(by * 32 + dl) * 8192 + bx * 32 + ld] = t[ld][dl];
    }
}

// -------- code norms in fp64 (ascending d, matches reference order) ---------
__global__ void cnormk(const float* __restrict__ cbT, double* __restrict__ cn2) {
    int k = blockIdx.x * 256 + threadIdx.x;    // 8192
    double s = 0.0;
    for (int d = 0; d < 256; ++d) {
        double c = (double)cbT[(size_t)d * 8192 + k];
        s += c * c;
    }
    cn2[k] = s;
}

// -------- proj init: feat = pb broadcast ------------------------------------
__global__ void projinitk(const float* __restrict__ pb, float* __restrict__ feat) {
    int i = blockIdx.x * 256 + threadIdx.x;    // 7168
    feat[i] = pb[i & 255];
}

// -------- proj (K-split x8): feat[r][d] += enc[r-chunk] . pw[d-chunk] -------
__global__ void projk(const float* __restrict__ enc, const float* __restrict__ pw,
                      float* __restrict__ feat) {
    int d = blockIdx.x & 255; int ch = blockIdx.x >> 8;    // 2048 blocks
    int k0 = ch * 4096;
    float acc[28];
    #pragma unroll
    for (int e = 0; e < 28; ++e) acc[e] = 0.f;
    const float* wrow = pw + (size_t)d * 32768 + k0;
    for (int k = threadIdx.x; k < 4096; k += 256) {
        float wv = wrow[k];
        #pragma unroll
        for (int e = 0; e < 28; ++e) acc[e] += enc[(size_t)e * 32768 + k0 + k] * wv;
    }
    __shared__ float red[4 * 28];
    #pragma unroll
    for (int e = 0; e < 28; ++e) {
        float v = acc[e];
        #pragma unroll
        for (int o = 32; o > 0; o >>= 1) v += __shfl_down(v, o, 64);
        if ((threadIdx.x & 63) == 0) red[(threadIdx.x >> 6) * 28 + e] = v;
    }
    __syncthreads();
    if (threadIdx.x < 28) {
        int e = threadIdx.x;
        int l = e >> 2, n = e & 3;
        float s = red[e] + red[28 + e] + red[56 + e] + red[84 + e];
        atomicAdd(&feat[(size_t)(n * 7 + l) * 256 + d], s);
    }
}

// -------- VQ: argmin over transposed codebook, fp64, 896 blocks -------------
__global__ void quantk(const float* __restrict__ feat, const float* __restrict__ cbT,
                       const double* __restrict__ cn2, unsigned long long* __restrict__ best) {
    int kc = blockIdx.x & 31, r = blockIdx.x >> 5;     // 896 = 32kc * 28r
    int k = kc * 256 + threadIdx.x;
    __shared__ float fs[256];
    fs[threadIdx.x] = feat[(size_t)r * 256 + threadIdx.x];
    __syncthreads();
    double dot = 0.0;
    for (int d = 0; d < 256; ++d)
        dot += (double)cbT[(size_t)d * 8192 + k] * (double)fs[d];
    float s = (float)(cn2[k] - 2.0 * dot);
    unsigned int bits = __float_as_uint(s);
    unsigned int key = (bits & 0x80000000u) ? ~bits : (bits | 0x80000000u);
    unsigned long long p = ((unsigned long long)key << 32) | (unsigned int)k;
    #pragma unroll
    for (int o = 32; o > 0; o >>= 1) {
        unsigned long long qv = __shfl_down(p, o, 64);
        if (qv < p) p = qv;
    }
    if ((threadIdx.x & 63) == 0) atomicMin(&best[r], p);
}

__global__ void gatherk(const unsigned long long* __restrict__ best,
                        const float* __restrict__ feat, const float* __restrict__ cb,
                        float* __restrict__ dout, float* __restrict__ quant,
                        float* __restrict__ acc) {
    int r = blockIdx.x;
    int d = threadIdx.x;
    int idx = (int)(best[r] & 0xFFFFFFFFull);
    float q = cb[(size_t)idx * 256 + d];
    quant[r * 256 + d] = q;
    dout[28 + r * 256 + d] = q;
    if (d == 0) dout[r] = (float)idx;
    float df = feat[r * 256 + d] - q;
    float v = df * df;
    #pragma unroll
    for (int o = 32; o > 0; o >>= 1) v += __shfl_down(v, o, 64);
    if ((d & 63) == 0) atomicAdd(&acc[0], v);
}

__global__ void gxk(const float* __restrict__ quant, const float* __restrict__ wih,
                    const float* __restrict__ bih, float* __restrict__ gx) {
    int o = blockIdx.x * 256 + threadIdx.x;
    int g = o % 768; int t = (o / 768) % 6; int n = o / (768 * 6);
    const float* q = quant + (size_t)(n * 7 + t) * 256;
    const float* w = wih + (size_t)g * 256;
    float s = bih[g];
    #pragma unroll 4
    for (int d = 0; d < 256; ++d) s += q[d] * w[d];
    gx[o] = s;
}

// -------- all 6 GRU steps in one kernel (block = batch b) -------------------
__global__ void gru_allk(const float* __restrict__ gx, const float* __restrict__ wt,
                         const float* __restrict__ bhh, const float* __restrict__ feat,
                         float* __restrict__ acc) {
    int b = blockIdx.x;        // 4
    int d = threadIdx.x;       // 256
    __shared__ float hs[256];
    hs[d] = 0.f;
    __syncthreads();
    float ctx = 0.f;
    for (int t = 0; t < 6; ++t) {
        float g0 = bhh[d], g1 = bhh[256 + d], g2 = bhh[512 + d];
        #pragma unroll 4
        for (int k = 0; k < 256; ++k) {
            float hv = hs[k];
            const float* wr = wt + (size_t)k * 768;
            g0 += wr[d] * hv; g1 += wr[256 + d] * hv; g2 += wr[512 + d] * hv;
        }
        const float* gxr = gx + (size_t)(b * 6 + t) * 768;
        float xr = gxr[d], xz = gxr[256 + d], xn = gxr[512 + d];
        float rr = 1.f / (1.f + expf(-(xr + g0)));
        float zz = 1.f / (1.f + expf(-(xz + g1)));
        float nn = tanhf(xn + rr * g2);
        float h2 = (1.f - zz) * nn + zz * hs[d];
        __syncthreads();
        hs[d] = h2;
        __syncthreads();
        float df = h2 - feat[(size_t)(b * 7 + t + 1) * 256 + d];
        ctx += df * df;
    }
    #pragma unroll
    for (int o = 32; o > 0; o >>= 1) ctx += __shfl_down(ctx, o, 64);
    if ((d & 63) == 0) atomicAdd(&acc[1], ctx);
}

__global__ void fink(const float* __restrict__ acc, float* __restrict__ dout) {
    float comm = acc[0] / 7168.f;
    float ctx  = acc[1] / 6144.f;
    dout[7196] = comm;
    dout[7197] = comm;
    dout[7198] = ctx;
    dout[7199] = comm + 0.25f * comm + 0.1f * ctx;
}

// ---------------------------------------------------------------------------
extern "C" void kernel_launch(void* const* d_in, const int* in_sizes, int n_in,
                              void* d_out, int out_size, void* d_ws, size_t ws_size,
                              hipStream_t stream) {
    (void)in_sizes; (void)n_in; (void)out_size; (void)ws_size;
    const float* x    = (const float*)d_in[0];
    const float* c1w  = (const float*)d_in[1];
    const float* c1b  = (const float*)d_in[2];
    const float* bn1g = (const float*)d_in[3];
    const float* bn1b = (const float*)d_in[4];
    const float* c2w  = (const float*)d_in[5];
    const float* c2b  = (const float*)d_in[6];
    const float* bn2g = (const float*)d_in[7];
    const float* bn2b = (const float*)d_in[8];
    const float* c3w  = (const float*)d_in[9];
    const float* c3b  = (const float*)d_in[10];
    const float* bn3g = (const float*)d_in[11];
    const float* bn3b = (const float*)d_in[12];
    const float* pw   = (const float*)d_in[13];
    const float* pb   = (const float*)d_in[14];
    const float* cb   = (const float*)d_in[15];
    const float* wih  = (const float*)d_in[16];
    const float* whh  = (const float*)d_in[17];
    const float* bih  = (const float*)d_in[18];
    const float* bhh  = (const float*)d_in[19];
    float* out = (float*)d_out;

    // ---- workspace layout (bytes) ----
    char* w = (char*)d_ws;
    float* A  = (float*)w;                         w += 75497472;   // conv2/3 outs; pmax/pmin + cbT alias
    float* PMAX = A;                                                // 18.87 MB (alias)
    float* PMIN = A + 4718592;                                      // 18.87 MB (alias)
    float* cbT = A;                                                 // 8 MB (alias, post-loop)
    double* cn2 = (double*)((char*)A + 8388608);                    // 64 KB (alias, post-loop)
    char*  SH = w;                                 w += 16293888;   // P3 hi/lo
    unsigned short* P3h = (unsigned short*)SH;
    unsigned short* P3l = (unsigned short*)(SH + 8146944);
    unsigned short* P2h = (unsigned short*)w;      w += 11980800;
    unsigned short* P2l = (unsigned short*)w;      w += 11980800;
    unsigned short* W2P = (unsigned short*)w;      w += 221184;
    unsigned short* W3P = (unsigned short*)w;      w += 884736;
    float* WT    = (float*)w;                      w += 786432;     // whh transposed [256][768]
    float* enc   = (float*)w;                      w += 3670016;
    float* feat  = (float*)w;                      w += 28672;
    float* quant = (float*)w;                      w += 28672;
    float* gx    = (float*)w;                      w += 73728;
    float* statsA = (float*)w;                     w += 21504;      // 21 x 256 floats
    float* acc    = (float*)w;                     w += 16;
    unsigned long long* best = (unsigned long long*)w;  w += 224;

    // ---- per-launch init ----
    hipMemsetAsync(P2h, 0, 11980800 * 2, stream);                  // P2 hi+lo pads
    hipMemsetAsync(statsA, 0, 21504 + 16, stream);                 // stats + acc
    hipMemsetAsync(best, 0xFF, 224, stream);
    prep2k<<<432, 256, 0, stream>>>(c2w, W2P);
    prep3k<<<1728, 256, 0, stream>>>(c3w, W3P);
    prepwhhk<<<768, 256, 0, stream>>>(whh, WT);

    for (int l = 0; l < 7; ++l) {
        float* st1 = statsA + (l * 3 + 0) * 256;
        float* st2 = statsA + (l * 3 + 1) * 256;
        float* st3 = statsA + (l * 3 + 2) * 256;
        conv1k<<<768, 256, 0, stream>>>(x, c1w, c1b, PMAX, PMIN, st1, l * 8);
        bnpool1b<<<2304, 256, 0, stream>>>(PMAX, PMIN, st1, bn1g, bn1b, P2h, P2l);
        conv2k<<<768, 256, 0, stream>>>(P2h, P2l, W2P, c2b, A, st2);
        bnpool2k<<<1989, 256, 0, stream>>>(A, st2, bn2g, bn2b, P3h, P3l);
        conv3k<<<768, 256, 0, stream>>>(P3h, P3l, W3P, c3b, A, st3);
        bnavgk<<<512, 256, 0, stream>>>(A, st3, bn3g, bn3b, enc + (size_t)l * 131072);
    }

    // A is free now: build transposed codebook + norms in its space
    transck<<<2048, 256, 0, stream>>>(cb, cbT);
    cnormk<<<32, 256, 0, stream>>>(cbT, cn2);
    projinitk<<<28, 256, 0, stream>>>(pb, feat);
    projk<<<2048, 256, 0, stream>>>(enc, pw, feat);
    quantk<<<896, 256, 0, stream>>>(feat, cbT, cn2, best);
    gatherk<<<28, 256, 0, stream>>>(best, feat, cb, out, quant, acc);
    gxk<<<72, 256, 0, stream>>>(quant, wih, bih, gx);
    gru_allk<<<4, 256, 0, stream>>>(gx, WT, bhh, feat, acc);
    fink<<<1, 1, 0, stream>>>(acc, out);
}